// Round 9
// baseline (13344.331 us; speedup 1.0000x reference)
//
#include <hip/hip_runtime.h>

#define N_ALL 4096
#define N_LAB 1024
#define DIMF 1024
#define CAP 64
#define OVFCAP 32768
#define ALPHA_ 0.99f
#define NIT_CH 250
#define EPS_D 2.220446049250313e-16

struct __align__(8) Edge { unsigned j; float w; };

__device__ inline const float* xrow(const float* L, const float* U, int r) {
  return (r < N_LAB) ? (L + (size_t)r * DIMF) : (U + (size_t)(r - N_LAB) * DIMF);
}

// ------- label-layout probe: flag=1 if buffer is int64, 0 if int32 -------
__global__ __launch_bounds__(256) void labfmt_k(const int* __restrict__ lab,
                                                int* __restrict__ flag) {
  const long long* l64 = (const long long*)lab;
  int bad = 0;
  for (int k = threadIdx.x; k < 512; k += 256) {
    long long v = l64[k];
    if (v != 0 && v != 1) bad = 1;
  }
  __shared__ int sbad[4];
  unsigned long long m = __ballot(bad);
  if ((threadIdx.x & 63) == 0) sbad[threadIdx.x >> 6] = (m != 0ull);
  __syncthreads();
  if (threadIdx.x == 0)
    flag[0] = (sbad[0] | sbad[1] | sbad[2] | sbad[3]) ? 0 : 1;
}

// ---------------- row squared norms (fp64) — r6 verbatim ----------------
__global__ __launch_bounds__(256) void sqd_k(const float* __restrict__ L,
                                             const float* __restrict__ U,
                                             double* __restrict__ sqd) {
  const int row = blockIdx.x;
  const int tid = threadIdx.x;
  const float* src = xrow(L, U, row);
  float4 v = ((const float4*)src)[tid];
  double s = (double)v.x * v.x + (double)v.y * v.y +
             (double)v.z * v.z + (double)v.w * v.w;
#pragma unroll
  for (int d = 32; d >= 1; d >>= 1) s += __shfl_xor(s, d);
  __shared__ double wsum[4];
  if ((tid & 63) == 0) wsum[tid >> 6] = s;
  __syncthreads();
  if (tid == 0) sqd[row] = wsum[0] + wsum[1] + wsum[2] + wsum[3];
}

// ------- dense Gram fp64 -> W, r6 verbatim (16x16 tile) -------
__global__ __launch_bounds__(256) void gram_k(const float* __restrict__ L,
                                              const float* __restrict__ U,
                                              const double* __restrict__ sqd,
                                              float* __restrict__ W) {
  __shared__ float As[16][17], Bs[16][17];
  const int tx = threadIdx.x, ty = threadIdx.y;
  const int row = blockIdx.y * 16 + ty;
  const int col = blockIdx.x * 16 + tx;
  const float* ar = xrow(L, U, row);
  const float* brl = xrow(L, U, blockIdx.x * 16 + ty);
  double acc = 0.0;
  for (int k0 = 0; k0 < DIMF; k0 += 16) {
    As[ty][tx] = ar[k0 + tx];
    Bs[ty][tx] = brl[k0 + tx];
    __syncthreads();
#pragma unroll
    for (int k = 0; k < 16; ++k)
      acc += (double)As[ty][k] * (double)Bs[tx][k];
    __syncthreads();
  }
  double dist = (sqd[row] + sqd[col] - 2.0 * acc) * (1.0 / 1024.0);
  double w = (row == col) ? 0.0 : exp(-0.5 * dist);
  W[(size_t)row * N_ALL + col] = (float)w;
}

// ------- exact top-4 per row — r6 verbatim -------
__global__ __launch_bounds__(256) void top4_k(const float* __restrict__ W,
                                              unsigned* __restrict__ t4i) {
  const int wave = threadIdx.x >> 6, lane = threadIdx.x & 63;
  const int row = blockIdx.x * 4 + wave;
  const float* Wr = W + (size_t)row * N_ALL;
  unsigned picked[4];
  for (int pick = 0; pick < 4; ++pick) {
    unsigned long long best = 0;
    for (int j = lane; j < N_ALL; j += 64) {
      bool skip = false;
      for (int q = 0; q < pick; ++q) skip |= (picked[q] == (unsigned)j);
      if (skip) continue;
      float v = Wr[j];  // >=0; positive float bits are order-monotone
      unsigned long long key = ((unsigned long long)__float_as_uint(v) << 32) |
                               (unsigned long long)(0xFFFFFFFFu - (unsigned)j);
      if (key > best) best = key;
    }
#pragma unroll
    for (int d = 32; d >= 1; d >>= 1) {
      unsigned long long o = __shfl_xor(best, d);
      if (o > best) best = o;
    }
    picked[pick] = 0xFFFFFFFFu - (unsigned)(best & 0xFFFFFFFFull);
  }
  if (lane == 0) {
#pragma unroll
    for (int q = 0; q < 4; ++q) t4i[row * 4 + q] = picked[q];
  }
}

// ------- dense mask (in place) + f64 row sums -> Dis — r6 verbatim -------
__global__ __launch_bounds__(256) void maskD_k(const unsigned* __restrict__ t4i,
                                               float* __restrict__ W,
                                               float* __restrict__ Dis) {
  const int i = blockIdx.x;
  const int tid = threadIdx.x;
  const uint4 mine = ((const uint4*)t4i)[i];
  float* Wr = W + (size_t)i * N_ALL;
  double ds = 0.0;
  for (int s = 0; s < 16; ++s) {
    int j = tid + 256 * s;
    uint4 tj = ((const uint4*)t4i)[j];
    bool keep = (mine.x == (unsigned)j) | (mine.y == (unsigned)j) |
                (mine.z == (unsigned)j) | (mine.w == (unsigned)j) |
                (tj.x == (unsigned)i) | (tj.y == (unsigned)i) |
                (tj.z == (unsigned)i) | (tj.w == (unsigned)i);
    keep = keep && (j != i);
    float w = keep ? Wr[j] : 0.0f;
    Wr[j] = w;
    ds += (double)w;
  }
#pragma unroll
  for (int d = 32; d >= 1; d >>= 1) ds += __shfl_xor(ds, d);
  __shared__ double scr[4];
  if ((tid & 63) == 0) scr[tid >> 6] = ds;
  __syncthreads();
  if (tid == 0) {
    double D = scr[0] + scr[1] + scr[2] + scr[3];
    Dis[i] = (float)sqrt(1.0 / (D + EPS_D));
  }
}

// ------- S = Dis_i * M * Dis_j (in place) — r6 verbatim -------
__global__ __launch_bounds__(256) void scale_k(float* __restrict__ W,
                                               const float* __restrict__ Dis) {
  const int i = blockIdx.x;
  const int tid = threadIdx.x;
  const float di = Dis[i];
  float* Wr = W + (size_t)i * N_ALL;
  for (int s = 0; s < 16; ++s) {
    int j = tid + 256 * s;
    Wr[j] = Wr[j] * di * Dis[j];
  }
}

// ------- count nonzeros per S row (full degree, no clamp) -------
__global__ __launch_bounds__(256) void cnt_k(const float* __restrict__ S,
                                             unsigned* __restrict__ nn) {
  const int wave = threadIdx.x >> 6, lane = threadIdx.x & 63;
  const int i = blockIdx.x * 4 + wave;
  const float* Sr = S + (size_t)i * N_ALL;
  unsigned base = 0;
  for (int j0 = 0; j0 < N_ALL; j0 += 64) {
    unsigned long long m = __ballot(Sr[j0 + lane] != 0.0f);
    base += (unsigned)__popcll(m);
  }
  if (lane == 0) nn[i] = base;
}

// ------- exclusive scan of max(deg-CAP, 0) -> overflow offsets (1 wave) -------
__global__ __launch_bounds__(64) void scan_k(const unsigned* __restrict__ nn,
                                             unsigned* __restrict__ ovfOff) {
  const int lane = threadIdx.x;
  unsigned running = 0;
  for (int j0 = 0; j0 < N_ALL; j0 += 64) {
    int v = (int)nn[j0 + lane] - CAP;
    if (v < 0) v = 0;
    int incl = v;
#pragma unroll
    for (int d = 1; d < 64; d <<= 1) {
      int t = __shfl_up(incl, d);
      if (lane >= d) incl += t;
    }
    ovfOff[j0 + lane] = running + (unsigned)(incl - v);
    running += (unsigned)__shfl(incl, 63);
  }
}

// ------- fill ELL (pos<CAP) + CSR overflow (pos>=CAP); j-ascending order -------
__global__ __launch_bounds__(256) void fill_k(const float* __restrict__ S,
                                              const unsigned* __restrict__ ovfOff,
                                              Edge* __restrict__ adjT,
                                              Edge* __restrict__ ovf) {
  const int wave = threadIdx.x >> 6, lane = threadIdx.x & 63;
  const int i = blockIdx.x * 4 + wave;
  const float* Sr = S + (size_t)i * N_ALL;
  const unsigned obase = ovfOff[i];
  unsigned base = 0;
  for (int j0 = 0; j0 < N_ALL; j0 += 64) {
    int j = j0 + lane;
    float s = Sr[j];
    bool keep = (s != 0.0f);
    unsigned long long m = __ballot(keep);
    if (keep) {
      unsigned pos = base + (unsigned)__popcll(m & ((1ull << lane) - 1ull));
      Edge e; e.j = (unsigned)j; e.w = s;
      if (pos < CAP) adjT[(size_t)pos * N_ALL + i] = e;
      else ovf[obase + pos - CAP] = e;
    }
    base += (unsigned)__popcll(m);
  }
}

// ---- single-block Chebyshev on (I - alpha*S), 2 RHS, ELL + overflow ----
// Same recurrence/bounds/iterations as validated r6 dense solve.
__global__ __launch_bounds__(1024) void cheb_k(const int* __restrict__ lab,
                                               const int* __restrict__ labflag,
                                               const unsigned* __restrict__ nn,
                                               const unsigned* __restrict__ ovfOff,
                                               const Edge* __restrict__ adjT,
                                               const Edge* __restrict__ ovf,
                                               float2* __restrict__ out) {
  __shared__ float2 dS[N_ALL];
  const int tid = threadIdx.x;
  const int isI64 = labflag[0];
  float2 x[4], r[4], dv[4];
  unsigned degE[4], degO[4], obase[4];
#pragma unroll
  for (int u = 0; u < 4; ++u) {
    int m = tid + u * 1024;
    unsigned deg = nn[m];
    degE[u] = (deg > CAP) ? CAP : deg;
    degO[u] = (deg > CAP) ? deg - CAP : 0;
    obase[u] = ovfOff[m];
    float2 b = make_float2(0.0f, 0.0f);
    if (m < N_LAB) {
      int c = isI64 ? lab[2 * m] : lab[m];
      b.x = (c == 0) ? 1.0f : 0.0f;
      b.y = (c == 1) ? 1.0f : 0.0f;
    }
    x[u] = make_float2(0.0f, 0.0f);
    r[u] = b;
    dv[u] = b;  // d = r/theta, theta = 1
    dS[m] = dv[u];
  }
  __syncthreads();
  const double theta = 1.0, delta = 0.992;
  const double sigma1 = theta / delta;
  double rho = delta / theta;
  for (int k = 0;; ++k) {
#pragma unroll
    for (int u = 0; u < 4; ++u) {
      int m = tid + u * 1024;
      float ax = 0.0f, ay = 0.0f;
      for (unsigned e = 0; e < degE[u]; ++e) {
        Edge ed = adjT[(size_t)e * N_ALL + m];
        float2 dj = dS[ed.j];
        ax += ed.w * dj.x;
        ay += ed.w * dj.y;
      }
      for (unsigned e = 0; e < degO[u]; ++e) {
        Edge ed = ovf[obase[u] + e];
        float2 dj = dS[ed.j];
        ax += ed.w * dj.x;
        ay += ed.w * dj.y;
      }
      x[u].x += dv[u].x; x[u].y += dv[u].y;
      r[u].x += ALPHA_ * ax - dv[u].x;
      r[u].y += ALPHA_ * ay - dv[u].y;
    }
    if (k == NIT_CH - 1) break;
    double rho_new = 1.0 / (2.0 * sigma1 - rho);
    float c1 = (float)(rho_new * rho);
    float c2 = (float)(2.0 * rho_new / delta);
    rho = rho_new;
    __syncthreads();  // SpMV reads of dS done before rewrite
#pragma unroll
    for (int u = 0; u < 4; ++u) {
      dv[u].x = c1 * dv[u].x + c2 * r[u].x;
      dv[u].y = c1 * dv[u].y + c2 * r[u].y;
      dS[tid + u * 1024] = dv[u];
    }
    __syncthreads();
  }
#pragma unroll
  for (int u = 1; u < 4; ++u) {
    int m = tid + u * 1024;
    out[m - N_LAB] = x[u];
  }
}

// ---------------- launch ----------------
extern "C" void kernel_launch(void* const* d_in, const int* in_sizes, int n_in,
                              void* d_out, int out_size, void* d_ws, size_t ws_size,
                              hipStream_t stream) {
  int iL = 0, iT = 1, iU = 2;
  for (int i = 0; i < n_in; ++i) {
    if (in_sizes[i] == N_LAB * DIMF) iL = i;
    else if (in_sizes[i] == (N_ALL - N_LAB) * DIMF) iU = i;
    else iT = i;
  }
  const float* L = (const float*)d_in[iL];
  const int* lab = (const int*)d_in[iT];
  const float* U = (const float*)d_in[iU];
  float2* out = (float2*)d_out;

  char* w = (char*)d_ws;
  size_t off = 0;
  auto alloc = [&](size_t bytes) {
    void* p = (void*)(w + off);
    off += (bytes + 255) & ~(size_t)255;
    return p;
  };
  float* W = (float*)alloc((size_t)N_ALL * N_ALL * 4);            // 64 MB: W -> M -> S
  double* sqd = (double*)alloc(N_ALL * 8);
  unsigned* t4i = (unsigned*)alloc(N_ALL * 4 * 4);
  float* Dis = (float*)alloc(N_ALL * 4);
  unsigned* nn = (unsigned*)alloc(N_ALL * 4);
  unsigned* ovfOff = (unsigned*)alloc(N_ALL * 4);
  int* labflag = (int*)alloc(256);
  Edge* adjT = (Edge*)alloc((size_t)CAP * N_ALL * sizeof(Edge));  // 2 MB
  Edge* ovf = (Edge*)alloc((size_t)OVFCAP * sizeof(Edge));        // 256 KB
  if (off > ws_size) return;  // diagnostic: out stays 0 -> absmax == ref max

  labfmt_k<<<1, 256, 0, stream>>>(lab, labflag);
  sqd_k<<<N_ALL, 256, 0, stream>>>(L, U, sqd);
  gram_k<<<dim3(256, 256), dim3(16, 16), 0, stream>>>(L, U, sqd, W);
  top4_k<<<N_ALL / 4, 256, 0, stream>>>(W, t4i);
  maskD_k<<<N_ALL, 256, 0, stream>>>(t4i, W, Dis);
  scale_k<<<N_ALL, 256, 0, stream>>>(W, Dis);
  cnt_k<<<N_ALL / 4, 256, 0, stream>>>(W, nn);
  scan_k<<<1, 64, 0, stream>>>(nn, ovfOff);
  fill_k<<<N_ALL / 4, 256, 0, stream>>>(W, ovfOff, adjT, ovf);
  cheb_k<<<1, 1024, 0, stream>>>(lab, labflag, nn, ovfOff, adjT, ovf, out);
}

// Round 10
// 9068.927 us; speedup vs baseline: 1.4714x; 1.4714x over previous
//
#include <hip/hip_runtime.h>

#define N_ALL 4096
#define N_LAB 1024
#define DIMF 1024
#define CAP 64
#define OVFCAP 32768
#define HUBCAP 512
#define ALPHA_ 0.99f
#define NIT_CH 250
#define EPS_D 2.220446049250313e-16

struct __align__(8) Edge { unsigned j; float w; };

__device__ inline const float* xrow(const float* L, const float* U, int r) {
  return (r < N_LAB) ? (L + (size_t)r * DIMF) : (U + (size_t)(r - N_LAB) * DIMF);
}

// ------- label-layout probe: flag=1 if buffer is int64, 0 if int32 -------
__global__ __launch_bounds__(256) void labfmt_k(const int* __restrict__ lab,
                                                int* __restrict__ flag) {
  const long long* l64 = (const long long*)lab;
  int bad = 0;
  for (int k = threadIdx.x; k < 512; k += 256) {
    long long v = l64[k];
    if (v != 0 && v != 1) bad = 1;
  }
  __shared__ int sbad[4];
  unsigned long long m = __ballot(bad);
  if ((threadIdx.x & 63) == 0) sbad[threadIdx.x >> 6] = (m != 0ull);
  __syncthreads();
  if (threadIdx.x == 0)
    flag[0] = (sbad[0] | sbad[1] | sbad[2] | sbad[3]) ? 0 : 1;
}

// ---------------- row squared norms (fp64) — r6 verbatim ----------------
__global__ __launch_bounds__(256) void sqd_k(const float* __restrict__ L,
                                             const float* __restrict__ U,
                                             double* __restrict__ sqd) {
  const int row = blockIdx.x;
  const int tid = threadIdx.x;
  const float* src = xrow(L, U, row);
  float4 v = ((const float4*)src)[tid];
  double s = (double)v.x * v.x + (double)v.y * v.y +
             (double)v.z * v.z + (double)v.w * v.w;
#pragma unroll
  for (int d = 32; d >= 1; d >>= 1) s += __shfl_xor(s, d);
  __shared__ double wsum[4];
  if ((tid & 63) == 0) wsum[tid >> 6] = s;
  __syncthreads();
  if (tid == 0) sqd[row] = wsum[0] + wsum[1] + wsum[2] + wsum[3];
}

// ------- dense Gram fp64 -> W; 32x32 tile, 2x2/thread; k-order == r6 (bitwise) -------
__global__ __launch_bounds__(256) void gram_k(const float* __restrict__ L,
                                              const float* __restrict__ U,
                                              const double* __restrict__ sqd,
                                              float* __restrict__ W) {
  __shared__ float As[32][20], Bs[32][20];  // stride 80 B = 5*16 B: b128-aligned
  const int tx = threadIdx.x, ty = threadIdx.y;  // 16x16
  const int tid = ty * 16 + tx;
  const int br = blockIdx.y * 32, bc = blockIdx.x * 32;
  const int lr = tid >> 3;            // 0..31
  const int lc = (tid & 7) * 2;       // 0..14
  const float* ga = xrow(L, U, br + lr);
  const float* gb = xrow(L, U, bc + lr);
  double a00 = 0.0, a01 = 0.0, a10 = 0.0, a11 = 0.0;
  for (int k0 = 0; k0 < DIMF; k0 += 16) {
    float2 va = *(const float2*)(ga + k0 + lc);
    float2 vb = *(const float2*)(gb + k0 + lc);
    __syncthreads();
    As[lr][lc] = va.x; As[lr][lc + 1] = va.y;
    Bs[lr][lc] = vb.x; Bs[lr][lc + 1] = vb.y;
    __syncthreads();
#pragma unroll
    for (int kk = 0; kk < 4; ++kk) {
      float4 av0 = *(const float4*)&As[ty][kk * 4];
      float4 av1 = *(const float4*)&As[ty + 16][kk * 4];
      float4 bv0 = *(const float4*)&Bs[tx][kk * 4];
      float4 bv1 = *(const float4*)&Bs[tx + 16][kk * 4];
      a00 += (double)av0.x * bv0.x; a01 += (double)av0.x * bv1.x;
      a10 += (double)av1.x * bv0.x; a11 += (double)av1.x * bv1.x;
      a00 += (double)av0.y * bv0.y; a01 += (double)av0.y * bv1.y;
      a10 += (double)av1.y * bv0.y; a11 += (double)av1.y * bv1.y;
      a00 += (double)av0.z * bv0.z; a01 += (double)av0.z * bv1.z;
      a10 += (double)av1.z * bv0.z; a11 += (double)av1.z * bv1.z;
      a00 += (double)av0.w * bv0.w; a01 += (double)av0.w * bv1.w;
      a10 += (double)av1.w * bv0.w; a11 += (double)av1.w * bv1.w;
    }
  }
  const int r0 = br + ty, r1 = br + ty + 16;
  const int c0 = bc + tx, c1 = bc + tx + 16;
  double s_r0 = sqd[r0], s_r1 = sqd[r1], s_c0 = sqd[c0], s_c1 = sqd[c1];
  double d00 = (s_r0 + s_c0 - 2.0 * a00) * (1.0 / 1024.0);
  double d01 = (s_r0 + s_c1 - 2.0 * a01) * (1.0 / 1024.0);
  double d10 = (s_r1 + s_c0 - 2.0 * a10) * (1.0 / 1024.0);
  double d11 = (s_r1 + s_c1 - 2.0 * a11) * (1.0 / 1024.0);
  W[(size_t)r0 * N_ALL + c0] = (r0 == c0) ? 0.0f : (float)exp(-0.5 * d00);
  W[(size_t)r0 * N_ALL + c1] = (r0 == c1) ? 0.0f : (float)exp(-0.5 * d01);
  W[(size_t)r1 * N_ALL + c0] = (r1 == c0) ? 0.0f : (float)exp(-0.5 * d10);
  W[(size_t)r1 * N_ALL + c1] = (r1 == c1) ? 0.0f : (float)exp(-0.5 * d11);
}

// ------- exact top-4 per row — r6 verbatim -------
__global__ __launch_bounds__(256) void top4_k(const float* __restrict__ W,
                                              unsigned* __restrict__ t4i) {
  const int wave = threadIdx.x >> 6, lane = threadIdx.x & 63;
  const int row = blockIdx.x * 4 + wave;
  const float* Wr = W + (size_t)row * N_ALL;
  unsigned picked[4];
  for (int pick = 0; pick < 4; ++pick) {
    unsigned long long best = 0;
    for (int j = lane; j < N_ALL; j += 64) {
      bool skip = false;
      for (int q = 0; q < pick; ++q) skip |= (picked[q] == (unsigned)j);
      if (skip) continue;
      float v = Wr[j];
      unsigned long long key = ((unsigned long long)__float_as_uint(v) << 32) |
                               (unsigned long long)(0xFFFFFFFFu - (unsigned)j);
      if (key > best) best = key;
    }
#pragma unroll
    for (int d = 32; d >= 1; d >>= 1) {
      unsigned long long o = __shfl_xor(best, d);
      if (o > best) best = o;
    }
    picked[pick] = 0xFFFFFFFFu - (unsigned)(best & 0xFFFFFFFFull);
  }
  if (lane == 0) {
#pragma unroll
    for (int q = 0; q < 4; ++q) t4i[row * 4 + q] = picked[q];
  }
}

// ------- dense mask (in place) + f64 row sums -> Dis — r6 verbatim -------
__global__ __launch_bounds__(256) void maskD_k(const unsigned* __restrict__ t4i,
                                               float* __restrict__ W,
                                               float* __restrict__ Dis) {
  const int i = blockIdx.x;
  const int tid = threadIdx.x;
  const uint4 mine = ((const uint4*)t4i)[i];
  float* Wr = W + (size_t)i * N_ALL;
  double ds = 0.0;
  for (int s = 0; s < 16; ++s) {
    int j = tid + 256 * s;
    uint4 tj = ((const uint4*)t4i)[j];
    bool keep = (mine.x == (unsigned)j) | (mine.y == (unsigned)j) |
                (mine.z == (unsigned)j) | (mine.w == (unsigned)j) |
                (tj.x == (unsigned)i) | (tj.y == (unsigned)i) |
                (tj.z == (unsigned)i) | (tj.w == (unsigned)i);
    keep = keep && (j != i);
    float w = keep ? Wr[j] : 0.0f;
    Wr[j] = w;
    ds += (double)w;
  }
#pragma unroll
  for (int d = 32; d >= 1; d >>= 1) ds += __shfl_xor(ds, d);
  __shared__ double scr[4];
  if ((tid & 63) == 0) scr[tid >> 6] = ds;
  __syncthreads();
  if (tid == 0) {
    double D = scr[0] + scr[1] + scr[2] + scr[3];
    Dis[i] = (float)sqrt(1.0 / (D + EPS_D));
  }
}

// ------- S = Dis_i * M * Dis_j (in place) — r6 verbatim -------
__global__ __launch_bounds__(256) void scale_k(float* __restrict__ W,
                                               const float* __restrict__ Dis) {
  const int i = blockIdx.x;
  const int tid = threadIdx.x;
  const float di = Dis[i];
  float* Wr = W + (size_t)i * N_ALL;
  for (int s = 0; s < 16; ++s) {
    int j = tid + 256 * s;
    Wr[j] = Wr[j] * di * Dis[j];
  }
}

// ------- count nonzeros per S row — r9 verbatim -------
__global__ __launch_bounds__(256) void cnt_k(const float* __restrict__ S,
                                             unsigned* __restrict__ nn) {
  const int wave = threadIdx.x >> 6, lane = threadIdx.x & 63;
  const int i = blockIdx.x * 4 + wave;
  const float* Sr = S + (size_t)i * N_ALL;
  unsigned base = 0;
  for (int j0 = 0; j0 < N_ALL; j0 += 64) {
    unsigned long long m = __ballot(Sr[j0 + lane] != 0.0f);
    base += (unsigned)__popcll(m);
  }
  if (lane == 0) nn[i] = base;
}

// ------- scan: overflow offsets + deterministic hub list (deg > CAP) -------
__global__ __launch_bounds__(64) void scan_k(const unsigned* __restrict__ nn,
                                             unsigned* __restrict__ ovfOff,
                                             unsigned* __restrict__ hubRow,
                                             int* __restrict__ hubid,
                                             unsigned* __restrict__ nHub) {
  const int lane = threadIdx.x;
  unsigned running = 0, nh = 0;
  for (int j0 = 0; j0 < N_ALL; j0 += 64) {
    int deg = (int)nn[j0 + lane];
    int v = deg - CAP;
    if (v < 0) v = 0;
    int incl = v;
#pragma unroll
    for (int d = 1; d < 64; d <<= 1) {
      int t = __shfl_up(incl, d);
      if (lane >= d) incl += t;
    }
    ovfOff[j0 + lane] = running + (unsigned)(incl - v);
    running += (unsigned)__shfl(incl, 63);
    bool ishub = (deg > CAP);
    unsigned long long mb = __ballot(ishub);
    unsigned hpos = nh + (unsigned)__popcll(mb & ((1ull << lane) - 1ull));
    if (ishub && hpos < HUBCAP) {
      hubRow[hpos] = (unsigned)(j0 + lane);
      hubid[j0 + lane] = (int)hpos;
    } else {
      hubid[j0 + lane] = ishub ? -2 : -1;  // -2 cannot happen (<=504 hubs)
    }
    nh += (unsigned)__popcll(mb);
  }
  if (lane == 0) nHub[0] = (nh > HUBCAP) ? HUBCAP : nh;
}

// ------- fill ELL (pos<CAP) + CSR overflow; j-ascending — r9 verbatim -------
__global__ __launch_bounds__(256) void fill_k(const float* __restrict__ S,
                                              const unsigned* __restrict__ ovfOff,
                                              Edge* __restrict__ adjT,
                                              Edge* __restrict__ ovf) {
  const int wave = threadIdx.x >> 6, lane = threadIdx.x & 63;
  const int i = blockIdx.x * 4 + wave;
  const float* Sr = S + (size_t)i * N_ALL;
  const unsigned obase = ovfOff[i];
  unsigned base = 0;
  for (int j0 = 0; j0 < N_ALL; j0 += 64) {
    int j = j0 + lane;
    float s = Sr[j];
    bool keep = (s != 0.0f);
    unsigned long long m = __ballot(keep);
    if (keep) {
      unsigned pos = base + (unsigned)__popcll(m & ((1ull << lane) - 1ull));
      Edge e; e.j = (unsigned)j; e.w = s;
      if (pos < CAP) adjT[(size_t)pos * N_ALL + i] = e;
      else ovf[obase + pos - CAP] = e;
    }
    base += (unsigned)__popcll(m);
  }
}

// ---- single-block Chebyshev, hub-aware: ELL per-thread + overflow per-wave ----
__global__ __launch_bounds__(1024) void cheb_k(const int* __restrict__ lab,
                                               const int* __restrict__ labflag,
                                               const unsigned* __restrict__ nn,
                                               const unsigned* __restrict__ ovfOff,
                                               const Edge* __restrict__ adjT,
                                               const Edge* __restrict__ ovf,
                                               const unsigned* __restrict__ hubRow,
                                               const int* __restrict__ hubid,
                                               const unsigned* __restrict__ nHub,
                                               float2* __restrict__ out) {
  __shared__ float2 dS[N_ALL];
  __shared__ float2 hubAcc[HUBCAP];
  __shared__ unsigned hCnt[HUBCAP];
  __shared__ unsigned hBase[HUBCAP];
  const int tid = threadIdx.x;
  const int wave = tid >> 6, lane = tid & 63;
  const int isI64 = labflag[0];
  const int nH = (int)nHub[0];
  for (int h = tid; h < nH; h += 1024) {
    unsigned m = hubRow[h];
    hCnt[h] = nn[m] - CAP;
    hBase[h] = ovfOff[m];
  }
  float2 x[4], r[4], dv[4];
  unsigned degE[4];
  int hid[4];
#pragma unroll
  for (int u = 0; u < 4; ++u) {
    int m = tid + u * 1024;
    unsigned deg = nn[m];
    degE[u] = (deg > CAP) ? CAP : deg;
    hid[u] = hubid[m];
    float2 b = make_float2(0.0f, 0.0f);
    if (m < N_LAB) {
      int c = isI64 ? lab[2 * m] : lab[m];
      b.x = (c == 0) ? 1.0f : 0.0f;
      b.y = (c == 1) ? 1.0f : 0.0f;
    }
    x[u] = make_float2(0.0f, 0.0f);
    r[u] = b;
    dv[u] = b;  // d = r/theta, theta = 1
    dS[m] = dv[u];
  }
  __syncthreads();
  const double theta = 1.0, delta = 0.992;
  const double sigma1 = theta / delta;
  double rho = delta / theta;
  for (int k = 0;; ++k) {
    // phase A: ELL gather (per thread) + hub overflow gather (per wave)
    float2 a[4];
#pragma unroll
    for (int u = 0; u < 4; ++u) {
      int m = tid + u * 1024;
      float ax = 0.0f, ay = 0.0f;
      for (unsigned e = 0; e < degE[u]; ++e) {
        Edge ed = adjT[(size_t)e * N_ALL + m];
        float2 dj = dS[ed.j];
        ax += ed.w * dj.x;
        ay += ed.w * dj.y;
      }
      a[u] = make_float2(ax, ay);
    }
    for (int h = wave; h < nH; h += 16) {
      unsigned cnt = hCnt[h], base = hBase[h];
      float hx = 0.0f, hy = 0.0f;
      for (unsigned e = lane; e < cnt; e += 64) {
        Edge ed = ovf[base + e];
        float2 dj = dS[ed.j];
        hx += ed.w * dj.x;
        hy += ed.w * dj.y;
      }
#pragma unroll
      for (int d = 32; d >= 1; d >>= 1) {
        hx += __shfl_xor(hx, d);
        hy += __shfl_xor(hy, d);
      }
      if (lane == 0) hubAcc[h] = make_float2(hx, hy);
    }
    __syncthreads();
    // phase B: finalize, update x/r, then d
#pragma unroll
    for (int u = 0; u < 4; ++u) {
      float ax = a[u].x, ay = a[u].y;
      if (hid[u] >= 0) {
        float2 hA = hubAcc[hid[u]];
        ax += hA.x;
        ay += hA.y;
      }
      x[u].x += dv[u].x; x[u].y += dv[u].y;
      r[u].x += ALPHA_ * ax - dv[u].x;
      r[u].y += ALPHA_ * ay - dv[u].y;
    }
    if (k == NIT_CH - 1) break;
    double rho_new = 1.0 / (2.0 * sigma1 - rho);
    float c1 = (float)(rho_new * rho);
    float c2 = (float)(2.0 * rho_new / delta);
    rho = rho_new;
#pragma unroll
    for (int u = 0; u < 4; ++u) {
      dv[u].x = c1 * dv[u].x + c2 * r[u].x;
      dv[u].y = c1 * dv[u].y + c2 * r[u].y;
      dS[tid + u * 1024] = dv[u];
    }
    __syncthreads();
  }
#pragma unroll
  for (int u = 1; u < 4; ++u) {
    int m = tid + u * 1024;
    out[m - N_LAB] = x[u];
  }
}

// ---------------- launch ----------------
extern "C" void kernel_launch(void* const* d_in, const int* in_sizes, int n_in,
                              void* d_out, int out_size, void* d_ws, size_t ws_size,
                              hipStream_t stream) {
  int iL = 0, iT = 1, iU = 2;
  for (int i = 0; i < n_in; ++i) {
    if (in_sizes[i] == N_LAB * DIMF) iL = i;
    else if (in_sizes[i] == (N_ALL - N_LAB) * DIMF) iU = i;
    else iT = i;
  }
  const float* L = (const float*)d_in[iL];
  const int* lab = (const int*)d_in[iT];
  const float* U = (const float*)d_in[iU];
  float2* out = (float2*)d_out;

  char* w = (char*)d_ws;
  size_t off = 0;
  auto alloc = [&](size_t bytes) {
    void* p = (void*)(w + off);
    off += (bytes + 255) & ~(size_t)255;
    return p;
  };
  float* W = (float*)alloc((size_t)N_ALL * N_ALL * 4);            // 64 MB
  double* sqd = (double*)alloc(N_ALL * 8);
  unsigned* t4i = (unsigned*)alloc(N_ALL * 4 * 4);
  float* Dis = (float*)alloc(N_ALL * 4);
  unsigned* nn = (unsigned*)alloc(N_ALL * 4);
  unsigned* ovfOff = (unsigned*)alloc(N_ALL * 4);
  unsigned* hubRow = (unsigned*)alloc(HUBCAP * 4);
  int* hubid = (int*)alloc(N_ALL * 4);
  unsigned* nHub = (unsigned*)alloc(256);
  int* labflag = (int*)alloc(256);
  Edge* adjT = (Edge*)alloc((size_t)CAP * N_ALL * sizeof(Edge));  // 2 MB
  Edge* ovf = (Edge*)alloc((size_t)OVFCAP * sizeof(Edge));        // 256 KB
  if (off > ws_size) return;

  labfmt_k<<<1, 256, 0, stream>>>(lab, labflag);
  sqd_k<<<N_ALL, 256, 0, stream>>>(L, U, sqd);
  gram_k<<<dim3(128, 128), dim3(16, 16), 0, stream>>>(L, U, sqd, W);
  top4_k<<<N_ALL / 4, 256, 0, stream>>>(W, t4i);
  maskD_k<<<N_ALL, 256, 0, stream>>>(t4i, W, Dis);
  scale_k<<<N_ALL, 256, 0, stream>>>(W, Dis);
  cnt_k<<<N_ALL / 4, 256, 0, stream>>>(W, nn);
  scan_k<<<1, 64, 0, stream>>>(nn, ovfOff, hubRow, hubid, nHub);
  fill_k<<<N_ALL / 4, 256, 0, stream>>>(W, ovfOff, adjT, ovf);
  cheb_k<<<1, 1024, 0, stream>>>(lab, labflag, nn, ovfOff, adjT, ovf,
                                 hubRow, hubid, nHub, out);
}

// Round 11
// 2535.508 us; speedup vs baseline: 5.2630x; 3.5768x over previous
//
#include <hip/hip_runtime.h>

#define N_ALL 4096
#define N_LAB 1024
#define DIMF 1024
#define EDGECAP 32768
#define ALPHA_ 0.99f
#define NIT_CH 250
#define EPS_D 2.220446049250313e-16

struct __align__(8) Edge { unsigned j; float w; };

__device__ inline const float* xrow(const float* L, const float* U, int r) {
  return (r < N_LAB) ? (L + (size_t)r * DIMF) : (U + (size_t)(r - N_LAB) * DIMF);
}

// ------- label-layout probe — r10 verbatim -------
__global__ __launch_bounds__(256) void labfmt_k(const int* __restrict__ lab,
                                                int* __restrict__ flag) {
  const long long* l64 = (const long long*)lab;
  int bad = 0;
  for (int k = threadIdx.x; k < 512; k += 256) {
    long long v = l64[k];
    if (v != 0 && v != 1) bad = 1;
  }
  __shared__ int sbad[4];
  unsigned long long m = __ballot(bad);
  if ((threadIdx.x & 63) == 0) sbad[threadIdx.x >> 6] = (m != 0ull);
  __syncthreads();
  if (threadIdx.x == 0)
    flag[0] = (sbad[0] | sbad[1] | sbad[2] | sbad[3]) ? 0 : 1;
}

// ---------------- row squared norms (fp64) — r10 verbatim ----------------
__global__ __launch_bounds__(256) void sqd_k(const float* __restrict__ L,
                                             const float* __restrict__ U,
                                             double* __restrict__ sqd) {
  const int row = blockIdx.x;
  const int tid = threadIdx.x;
  const float* src = xrow(L, U, row);
  float4 v = ((const float4*)src)[tid];
  double s = (double)v.x * v.x + (double)v.y * v.y +
             (double)v.z * v.z + (double)v.w * v.w;
#pragma unroll
  for (int d = 32; d >= 1; d >>= 1) s += __shfl_xor(s, d);
  __shared__ double wsum[4];
  if ((tid & 63) == 0) wsum[tid >> 6] = s;
  __syncthreads();
  if (tid == 0) sqd[row] = wsum[0] + wsum[1] + wsum[2] + wsum[3];
}

// ------- dense Gram fp64 -> W; 32x32 tile — r10 verbatim -------
__global__ __launch_bounds__(256) void gram_k(const float* __restrict__ L,
                                              const float* __restrict__ U,
                                              const double* __restrict__ sqd,
                                              float* __restrict__ W) {
  __shared__ float As[32][20], Bs[32][20];
  const int tx = threadIdx.x, ty = threadIdx.y;
  const int tid = ty * 16 + tx;
  const int br = blockIdx.y * 32, bc = blockIdx.x * 32;
  const int lr = tid >> 3;
  const int lc = (tid & 7) * 2;
  const float* ga = xrow(L, U, br + lr);
  const float* gb = xrow(L, U, bc + lr);
  double a00 = 0.0, a01 = 0.0, a10 = 0.0, a11 = 0.0;
  for (int k0 = 0; k0 < DIMF; k0 += 16) {
    float2 va = *(const float2*)(ga + k0 + lc);
    float2 vb = *(const float2*)(gb + k0 + lc);
    __syncthreads();
    As[lr][lc] = va.x; As[lr][lc + 1] = va.y;
    Bs[lr][lc] = vb.x; Bs[lr][lc + 1] = vb.y;
    __syncthreads();
#pragma unroll
    for (int kk = 0; kk < 4; ++kk) {
      float4 av0 = *(const float4*)&As[ty][kk * 4];
      float4 av1 = *(const float4*)&As[ty + 16][kk * 4];
      float4 bv0 = *(const float4*)&Bs[tx][kk * 4];
      float4 bv1 = *(const float4*)&Bs[tx + 16][kk * 4];
      a00 += (double)av0.x * bv0.x; a01 += (double)av0.x * bv1.x;
      a10 += (double)av1.x * bv0.x; a11 += (double)av1.x * bv1.x;
      a00 += (double)av0.y * bv0.y; a01 += (double)av0.y * bv1.y;
      a10 += (double)av1.y * bv0.y; a11 += (double)av1.y * bv1.y;
      a00 += (double)av0.z * bv0.z; a01 += (double)av0.z * bv1.z;
      a10 += (double)av1.z * bv0.z; a11 += (double)av1.z * bv1.z;
      a00 += (double)av0.w * bv0.w; a01 += (double)av0.w * bv1.w;
      a10 += (double)av1.w * bv0.w; a11 += (double)av1.w * bv1.w;
    }
  }
  const int r0 = br + ty, r1 = br + ty + 16;
  const int c0 = bc + tx, c1 = bc + tx + 16;
  double s_r0 = sqd[r0], s_r1 = sqd[r1], s_c0 = sqd[c0], s_c1 = sqd[c1];
  double d00 = (s_r0 + s_c0 - 2.0 * a00) * (1.0 / 1024.0);
  double d01 = (s_r0 + s_c1 - 2.0 * a01) * (1.0 / 1024.0);
  double d10 = (s_r1 + s_c0 - 2.0 * a10) * (1.0 / 1024.0);
  double d11 = (s_r1 + s_c1 - 2.0 * a11) * (1.0 / 1024.0);
  W[(size_t)r0 * N_ALL + c0] = (r0 == c0) ? 0.0f : (float)exp(-0.5 * d00);
  W[(size_t)r0 * N_ALL + c1] = (r0 == c1) ? 0.0f : (float)exp(-0.5 * d01);
  W[(size_t)r1 * N_ALL + c0] = (r1 == c0) ? 0.0f : (float)exp(-0.5 * d10);
  W[(size_t)r1 * N_ALL + c1] = (r1 == c1) ? 0.0f : (float)exp(-0.5 * d11);
}

// ------- exact top-4 per row — r10 verbatim -------
__global__ __launch_bounds__(256) void top4_k(const float* __restrict__ W,
                                              unsigned* __restrict__ t4i) {
  const int wave = threadIdx.x >> 6, lane = threadIdx.x & 63;
  const int row = blockIdx.x * 4 + wave;
  const float* Wr = W + (size_t)row * N_ALL;
  unsigned picked[4];
  for (int pick = 0; pick < 4; ++pick) {
    unsigned long long best = 0;
    for (int j = lane; j < N_ALL; j += 64) {
      bool skip = false;
      for (int q = 0; q < pick; ++q) skip |= (picked[q] == (unsigned)j);
      if (skip) continue;
      float v = Wr[j];
      unsigned long long key = ((unsigned long long)__float_as_uint(v) << 32) |
                               (unsigned long long)(0xFFFFFFFFu - (unsigned)j);
      if (key > best) best = key;
    }
#pragma unroll
    for (int d = 32; d >= 1; d >>= 1) {
      unsigned long long o = __shfl_xor(best, d);
      if (o > best) best = o;
    }
    picked[pick] = 0xFFFFFFFFu - (unsigned)(best & 0xFFFFFFFFull);
  }
  if (lane == 0) {
#pragma unroll
    for (int q = 0; q < 4; ++q) t4i[row * 4 + q] = picked[q];
  }
}

// ------- dense mask (in place) + f64 row sums -> Dis — r10 verbatim -------
__global__ __launch_bounds__(256) void maskD_k(const unsigned* __restrict__ t4i,
                                               float* __restrict__ W,
                                               float* __restrict__ Dis) {
  const int i = blockIdx.x;
  const int tid = threadIdx.x;
  const uint4 mine = ((const uint4*)t4i)[i];
  float* Wr = W + (size_t)i * N_ALL;
  double ds = 0.0;
  for (int s = 0; s < 16; ++s) {
    int j = tid + 256 * s;
    uint4 tj = ((const uint4*)t4i)[j];
    bool keep = (mine.x == (unsigned)j) | (mine.y == (unsigned)j) |
                (mine.z == (unsigned)j) | (mine.w == (unsigned)j) |
                (tj.x == (unsigned)i) | (tj.y == (unsigned)i) |
                (tj.z == (unsigned)i) | (tj.w == (unsigned)i);
    keep = keep && (j != i);
    float w = keep ? Wr[j] : 0.0f;
    Wr[j] = w;
    ds += (double)w;
  }
#pragma unroll
  for (int d = 32; d >= 1; d >>= 1) ds += __shfl_xor(ds, d);
  __shared__ double scr[4];
  if ((tid & 63) == 0) scr[tid >> 6] = ds;
  __syncthreads();
  if (tid == 0) {
    double D = scr[0] + scr[1] + scr[2] + scr[3];
    Dis[i] = (float)sqrt(1.0 / (D + EPS_D));
  }
}

// ------- S = Dis_i * M * Dis_j (in place) — r10 verbatim -------
__global__ __launch_bounds__(256) void scale_k(float* __restrict__ W,
                                               const float* __restrict__ Dis) {
  const int i = blockIdx.x;
  const int tid = threadIdx.x;
  const float di = Dis[i];
  float* Wr = W + (size_t)i * N_ALL;
  for (int s = 0; s < 16; ++s) {
    int j = tid + 256 * s;
    Wr[j] = Wr[j] * di * Dis[j];
  }
}

// ------- count nonzeros per S row — r10 verbatim -------
__global__ __launch_bounds__(256) void cnt_k(const float* __restrict__ S,
                                             unsigned* __restrict__ nn) {
  const int wave = threadIdx.x >> 6, lane = threadIdx.x & 63;
  const int i = blockIdx.x * 4 + wave;
  const float* Sr = S + (size_t)i * N_ALL;
  unsigned base = 0;
  for (int j0 = 0; j0 < N_ALL; j0 += 64) {
    unsigned long long m = __ballot(Sr[j0 + lane] != 0.0f);
    base += (unsigned)__popcll(m);
  }
  if (lane == 0) nn[i] = base;
}

// ------- exclusive scan of nn -> CSR rowPtr (single wave) -------
__global__ __launch_bounds__(64) void scanP_k(const unsigned* __restrict__ nn,
                                              unsigned* __restrict__ rowPtr) {
  const int lane = threadIdx.x;
  unsigned running = 0;
  for (int j0 = 0; j0 < N_ALL; j0 += 64) {
    int v = (int)nn[j0 + lane];
    int incl = v;
#pragma unroll
    for (int d = 1; d < 64; d <<= 1) {
      int t = __shfl_up(incl, d);
      if (lane >= d) incl += t;
    }
    rowPtr[j0 + lane] = running + (unsigned)(incl - v);
    running += (unsigned)__shfl(incl, 63);
  }
  if (lane == 0) rowPtr[N_ALL] = running;
}

// ------- CSR fill, j-ascending per row (ballot compaction, wave/row) -------
__global__ __launch_bounds__(256) void fillcsr_k(const float* __restrict__ S,
                                                 const unsigned* __restrict__ rowPtr,
                                                 Edge* __restrict__ edges) {
  const int wave = threadIdx.x >> 6, lane = threadIdx.x & 63;
  const int i = blockIdx.x * 4 + wave;
  const float* Sr = S + (size_t)i * N_ALL;
  unsigned base = rowPtr[i];
  for (int j0 = 0; j0 < N_ALL; j0 += 64) {
    int j = j0 + lane;
    float s = Sr[j];
    bool keep = (s != 0.0f);
    unsigned long long m = __ballot(keep);
    if (keep) {
      unsigned pos = base + (unsigned)__popcll(m & ((1ull << lane) - 1ull));
      Edge e; e.j = (unsigned)j; e.w = s;
      edges[pos] = e;
    }
    base += (unsigned)__popcll(m);
  }
}

// ------- Chebyshev state init: x=0, r=b, d=b (theta=1) -------
__global__ __launch_bounds__(256) void init_k(const int* __restrict__ lab,
                                              const int* __restrict__ labflag,
                                              float2* __restrict__ x,
                                              float2* __restrict__ r,
                                              float2* __restrict__ d) {
  const int m = blockIdx.x * 256 + threadIdx.x;
  const int isI64 = labflag[0];
  float2 b = make_float2(0.0f, 0.0f);
  if (m < N_LAB) {
    int c = isI64 ? lab[2 * m] : lab[m];
    b.x = (c == 0) ? 1.0f : 0.0f;
    b.y = (c == 1) ? 1.0f : 0.0f;
  }
  x[m] = make_float2(0.0f, 0.0f);
  r[m] = b;
  d[m] = b;
}

// ---- one Chebyshev iteration: wave per row; dIn read-only, dOut written ----
// a = (S dIn)_row;  x += dIn_row;  r += alpha*a - dIn_row;  dOut = c1*dIn + c2*r
__global__ __launch_bounds__(512) void chebit_k(const Edge* __restrict__ edges,
                                                const unsigned* __restrict__ rowPtr,
                                                const float2* __restrict__ dIn,
                                                float2* __restrict__ dOut,
                                                float2* __restrict__ x,
                                                float2* __restrict__ r,
                                                float c1, float c2, int last) {
  const int row = blockIdx.x * 8 + (threadIdx.x >> 6);
  const int lane = threadIdx.x & 63;
  const unsigned b0 = rowPtr[row], b1 = rowPtr[row + 1];
  float ax = 0.0f, ay = 0.0f;
  for (unsigned e = b0 + lane; e < b1; e += 64) {
    Edge ed = edges[e];
    float2 dj = dIn[ed.j];
    ax += ed.w * dj.x;
    ay += ed.w * dj.y;
  }
#pragma unroll
  for (int d = 32; d >= 1; d >>= 1) {
    ax += __shfl_xor(ax, d);
    ay += __shfl_xor(ay, d);
  }
  if (lane == 0) {
    float2 di = dIn[row], xi = x[row], ri = r[row];
    xi.x += di.x; xi.y += di.y;
    ri.x += ALPHA_ * ax - di.x;
    ri.y += ALPHA_ * ay - di.y;
    x[row] = xi;
    r[row] = ri;
    if (!last) {
      float2 dn;
      dn.x = c1 * di.x + c2 * ri.x;
      dn.y = c1 * di.y + c2 * ri.y;
      dOut[row] = dn;
    }
  }
}

// ------- emit queries -------
__global__ __launch_bounds__(256) void out_k(const float2* __restrict__ x,
                                             float2* __restrict__ out) {
  const int q = blockIdx.x * 256 + threadIdx.x;
  out[q] = x[N_LAB + q];
}

// ---------------- launch ----------------
extern "C" void kernel_launch(void* const* d_in, const int* in_sizes, int n_in,
                              void* d_out, int out_size, void* d_ws, size_t ws_size,
                              hipStream_t stream) {
  int iL = 0, iT = 1, iU = 2;
  for (int i = 0; i < n_in; ++i) {
    if (in_sizes[i] == N_LAB * DIMF) iL = i;
    else if (in_sizes[i] == (N_ALL - N_LAB) * DIMF) iU = i;
    else iT = i;
  }
  const float* L = (const float*)d_in[iL];
  const int* lab = (const int*)d_in[iT];
  const float* U = (const float*)d_in[iU];
  float2* out = (float2*)d_out;

  char* w = (char*)d_ws;
  size_t off = 0;
  auto alloc = [&](size_t bytes) {
    void* p = (void*)(w + off);
    off += (bytes + 255) & ~(size_t)255;
    return p;
  };
  float* W = (float*)alloc((size_t)N_ALL * N_ALL * 4);       // 64 MB
  double* sqd = (double*)alloc(N_ALL * 8);
  unsigned* t4i = (unsigned*)alloc(N_ALL * 4 * 4);
  float* Dis = (float*)alloc(N_ALL * 4);
  unsigned* nn = (unsigned*)alloc(N_ALL * 4);
  unsigned* rowPtr = (unsigned*)alloc((N_ALL + 1) * 4);
  int* labflag = (int*)alloc(256);
  Edge* edges = (Edge*)alloc((size_t)EDGECAP * sizeof(Edge));  // 256 KB
  float2* xv = (float2*)alloc(N_ALL * 8);
  float2* rv = (float2*)alloc(N_ALL * 8);
  float2* dv0 = (float2*)alloc(N_ALL * 8);
  float2* dv1 = (float2*)alloc(N_ALL * 8);
  if (off > ws_size) return;

  labfmt_k<<<1, 256, 0, stream>>>(lab, labflag);
  sqd_k<<<N_ALL, 256, 0, stream>>>(L, U, sqd);
  gram_k<<<dim3(128, 128), dim3(16, 16), 0, stream>>>(L, U, sqd, W);
  top4_k<<<N_ALL / 4, 256, 0, stream>>>(W, t4i);
  maskD_k<<<N_ALL, 256, 0, stream>>>(t4i, W, Dis);
  scale_k<<<N_ALL, 256, 0, stream>>>(W, Dis);
  cnt_k<<<N_ALL / 4, 256, 0, stream>>>(W, nn);
  scanP_k<<<1, 64, 0, stream>>>(nn, rowPtr);
  fillcsr_k<<<N_ALL / 4, 256, 0, stream>>>(W, rowPtr, edges);
  init_k<<<N_ALL / 256, 256, 0, stream>>>(lab, labflag, xv, rv, dv0);

  // Chebyshev scalar recurrence on host (bitwise-identical c1/c2 to r10).
  const double theta = 1.0, delta = 0.992;
  const double sigma1 = theta / delta;
  double rho = delta / theta;
  float2* dA = dv0;
  float2* dB = dv1;
  for (int k = 0; k < NIT_CH; ++k) {
    const int last = (k == NIT_CH - 1);
    const double rho_new = 1.0 / (2.0 * sigma1 - rho);
    const float c1 = (float)(rho_new * rho);
    const float c2 = (float)(2.0 * rho_new / delta);
    chebit_k<<<N_ALL / 8, 512, 0, stream>>>(edges, rowPtr, dA, dB, xv, rv,
                                            c1, c2, last);
    rho = rho_new;
    float2* t = dA; dA = dB; dB = t;
  }
  out_k<<<(N_ALL - N_LAB) / 256, 256, 0, stream>>>(xv, out);
}

// Round 12
// 1448.851 us; speedup vs baseline: 9.2103x; 1.7500x over previous
//
#include <hip/hip_runtime.h>

#define N_ALL 4096
#define N_LAB 1024
#define DIMF 1024
#define EDGECAP 32768
#define ALPHA_ 0.99f
#define NIT_CH 120
#define EPS_D 2.220446049250313e-16

struct __align__(8) Edge { unsigned j; float w; };

__device__ inline const float* xrow(const float* L, const float* U, int r) {
  return (r < N_LAB) ? (L + (size_t)r * DIMF) : (U + (size_t)(r - N_LAB) * DIMF);
}

// ------- label-layout probe — r11 verbatim -------
__global__ __launch_bounds__(256) void labfmt_k(const int* __restrict__ lab,
                                                int* __restrict__ flag) {
  const long long* l64 = (const long long*)lab;
  int bad = 0;
  for (int k = threadIdx.x; k < 512; k += 256) {
    long long v = l64[k];
    if (v != 0 && v != 1) bad = 1;
  }
  __shared__ int sbad[4];
  unsigned long long m = __ballot(bad);
  if ((threadIdx.x & 63) == 0) sbad[threadIdx.x >> 6] = (m != 0ull);
  __syncthreads();
  if (threadIdx.x == 0)
    flag[0] = (sbad[0] | sbad[1] | sbad[2] | sbad[3]) ? 0 : 1;
}

// ---------------- row squared norms (fp64) — r11 verbatim ----------------
__global__ __launch_bounds__(256) void sqd_k(const float* __restrict__ L,
                                             const float* __restrict__ U,
                                             double* __restrict__ sqd) {
  const int row = blockIdx.x;
  const int tid = threadIdx.x;
  const float* src = xrow(L, U, row);
  float4 v = ((const float4*)src)[tid];
  double s = (double)v.x * v.x + (double)v.y * v.y +
             (double)v.z * v.z + (double)v.w * v.w;
#pragma unroll
  for (int d = 32; d >= 1; d >>= 1) s += __shfl_xor(s, d);
  __shared__ double wsum[4];
  if ((tid & 63) == 0) wsum[tid >> 6] = s;
  __syncthreads();
  if (tid == 0) sqd[row] = wsum[0] + wsum[1] + wsum[2] + wsum[3];
}

// ------- dense Gram fp64 -> W; 32x32 tile; UPPER TRIANGLE ONLY + mirror -------
// acc(i,j) bitwise == acc(j,i) (commutative mul, same k-order), so mirrored
// stores reproduce the full-matrix kernel's W exactly.
__global__ __launch_bounds__(256) void gram_k(const float* __restrict__ L,
                                              const float* __restrict__ U,
                                              const double* __restrict__ sqd,
                                              float* __restrict__ W) {
  if (blockIdx.y > blockIdx.x) return;  // lower-triangle blocks: mirrored instead
  __shared__ float As[32][20], Bs[32][20];
  const int tx = threadIdx.x, ty = threadIdx.y;
  const int tid = ty * 16 + tx;
  const int br = blockIdx.y * 32, bc = blockIdx.x * 32;
  const int lr = tid >> 3;
  const int lc = (tid & 7) * 2;
  const float* ga = xrow(L, U, br + lr);
  const float* gb = xrow(L, U, bc + lr);
  double a00 = 0.0, a01 = 0.0, a10 = 0.0, a11 = 0.0;
  for (int k0 = 0; k0 < DIMF; k0 += 16) {
    float2 va = *(const float2*)(ga + k0 + lc);
    float2 vb = *(const float2*)(gb + k0 + lc);
    __syncthreads();
    As[lr][lc] = va.x; As[lr][lc + 1] = va.y;
    Bs[lr][lc] = vb.x; Bs[lr][lc + 1] = vb.y;
    __syncthreads();
#pragma unroll
    for (int kk = 0; kk < 4; ++kk) {
      float4 av0 = *(const float4*)&As[ty][kk * 4];
      float4 av1 = *(const float4*)&As[ty + 16][kk * 4];
      float4 bv0 = *(const float4*)&Bs[tx][kk * 4];
      float4 bv1 = *(const float4*)&Bs[tx + 16][kk * 4];
      a00 += (double)av0.x * bv0.x; a01 += (double)av0.x * bv1.x;
      a10 += (double)av1.x * bv0.x; a11 += (double)av1.x * bv1.x;
      a00 += (double)av0.y * bv0.y; a01 += (double)av0.y * bv1.y;
      a10 += (double)av1.y * bv0.y; a11 += (double)av1.y * bv1.y;
      a00 += (double)av0.z * bv0.z; a01 += (double)av0.z * bv1.z;
      a10 += (double)av1.z * bv0.z; a11 += (double)av1.z * bv1.z;
      a00 += (double)av0.w * bv0.w; a01 += (double)av0.w * bv1.w;
      a10 += (double)av1.w * bv0.w; a11 += (double)av1.w * bv1.w;
    }
  }
  const int r0 = br + ty, r1 = br + ty + 16;
  const int c0 = bc + tx, c1 = bc + tx + 16;
  double s_r0 = sqd[r0], s_r1 = sqd[r1], s_c0 = sqd[c0], s_c1 = sqd[c1];
  float w00 = (r0 == c0) ? 0.0f
      : (float)exp(-0.5 * ((s_r0 + s_c0 - 2.0 * a00) * (1.0 / 1024.0)));
  float w01 = (r0 == c1) ? 0.0f
      : (float)exp(-0.5 * ((s_r0 + s_c1 - 2.0 * a01) * (1.0 / 1024.0)));
  float w10 = (r1 == c0) ? 0.0f
      : (float)exp(-0.5 * ((s_r1 + s_c0 - 2.0 * a10) * (1.0 / 1024.0)));
  float w11 = (r1 == c1) ? 0.0f
      : (float)exp(-0.5 * ((s_r1 + s_c1 - 2.0 * a11) * (1.0 / 1024.0)));
  W[(size_t)r0 * N_ALL + c0] = w00;
  W[(size_t)r0 * N_ALL + c1] = w01;
  W[(size_t)r1 * N_ALL + c0] = w10;
  W[(size_t)r1 * N_ALL + c1] = w11;
  // mirror (sq-sum commutes; acc identical) — diagonal blocks rewrite same values
  W[(size_t)c0 * N_ALL + r0] = w00;
  W[(size_t)c1 * N_ALL + r0] = w01;
  W[(size_t)c0 * N_ALL + r1] = w10;
  W[(size_t)c1 * N_ALL + r1] = w11;
}

// ------- exact top-4 per row — r11 verbatim -------
__global__ __launch_bounds__(256) void top4_k(const float* __restrict__ W,
                                              unsigned* __restrict__ t4i) {
  const int wave = threadIdx.x >> 6, lane = threadIdx.x & 63;
  const int row = blockIdx.x * 4 + wave;
  const float* Wr = W + (size_t)row * N_ALL;
  unsigned picked[4];
  for (int pick = 0; pick < 4; ++pick) {
    unsigned long long best = 0;
    for (int j = lane; j < N_ALL; j += 64) {
      bool skip = false;
      for (int q = 0; q < pick; ++q) skip |= (picked[q] == (unsigned)j);
      if (skip) continue;
      float v = Wr[j];
      unsigned long long key = ((unsigned long long)__float_as_uint(v) << 32) |
                               (unsigned long long)(0xFFFFFFFFu - (unsigned)j);
      if (key > best) best = key;
    }
#pragma unroll
    for (int d = 32; d >= 1; d >>= 1) {
      unsigned long long o = __shfl_xor(best, d);
      if (o > best) best = o;
    }
    picked[pick] = 0xFFFFFFFFu - (unsigned)(best & 0xFFFFFFFFull);
  }
  if (lane == 0) {
#pragma unroll
    for (int q = 0; q < 4; ++q) t4i[row * 4 + q] = picked[q];
  }
}

// ------- dense mask (in place) + f64 row sums -> Dis + keep-count -> nn -------
__global__ __launch_bounds__(256) void maskD_k(const unsigned* __restrict__ t4i,
                                               float* __restrict__ W,
                                               float* __restrict__ Dis,
                                               unsigned* __restrict__ nn) {
  const int i = blockIdx.x;
  const int tid = threadIdx.x;
  const uint4 mine = ((const uint4*)t4i)[i];
  float* Wr = W + (size_t)i * N_ALL;
  double ds = 0.0;
  int kc = 0;
  for (int s = 0; s < 16; ++s) {
    int j = tid + 256 * s;
    uint4 tj = ((const uint4*)t4i)[j];
    bool keep = (mine.x == (unsigned)j) | (mine.y == (unsigned)j) |
                (mine.z == (unsigned)j) | (mine.w == (unsigned)j) |
                (tj.x == (unsigned)i) | (tj.y == (unsigned)i) |
                (tj.z == (unsigned)i) | (tj.w == (unsigned)i);
    keep = keep && (j != i);
    float w = keep ? Wr[j] : 0.0f;
    Wr[j] = w;
    ds += (double)w;
    kc += keep ? 1 : 0;
  }
#pragma unroll
  for (int d = 32; d >= 1; d >>= 1) {
    ds += __shfl_xor(ds, d);
    kc += __shfl_xor(kc, d);
  }
  __shared__ double scr[4];
  __shared__ int scc[4];
  if ((tid & 63) == 0) { scr[tid >> 6] = ds; scc[tid >> 6] = kc; }
  __syncthreads();
  if (tid == 0) {
    double D = scr[0] + scr[1] + scr[2] + scr[3];
    Dis[i] = (float)sqrt(1.0 / (D + EPS_D));
    nn[i] = (unsigned)(scc[0] + scc[1] + scc[2] + scc[3]);
  }
}

// ------- exclusive scan of nn -> CSR rowPtr (single wave) — r11 verbatim -------
__global__ __launch_bounds__(64) void scanP_k(const unsigned* __restrict__ nn,
                                              unsigned* __restrict__ rowPtr) {
  const int lane = threadIdx.x;
  unsigned running = 0;
  for (int j0 = 0; j0 < N_ALL; j0 += 64) {
    int v = (int)nn[j0 + lane];
    int incl = v;
#pragma unroll
    for (int d = 1; d < 64; d <<= 1) {
      int t = __shfl_up(incl, d);
      if (lane >= d) incl += t;
    }
    rowPtr[j0 + lane] = running + (unsigned)(incl - v);
    running += (unsigned)__shfl(incl, 63);
  }
  if (lane == 0) rowPtr[N_ALL] = running;
}

// ------- CSR fill from masked W with inline scaling; j-ascending -------
// w = (Wmask[i][j] * Dis[i]) * Dis[j]: same order as r11's scale_k -> bitwise.
__global__ __launch_bounds__(256) void fillcsr_k(const float* __restrict__ Wm,
                                                 const float* __restrict__ Dis,
                                                 const unsigned* __restrict__ rowPtr,
                                                 Edge* __restrict__ edges) {
  const int wave = threadIdx.x >> 6, lane = threadIdx.x & 63;
  const int i = blockIdx.x * 4 + wave;
  const float* Wr = Wm + (size_t)i * N_ALL;
  const float di = Dis[i];
  unsigned base = rowPtr[i];
  for (int j0 = 0; j0 < N_ALL; j0 += 64) {
    int j = j0 + lane;
    float s = Wr[j];
    bool keep = (s != 0.0f);
    unsigned long long m = __ballot(keep);
    if (keep) {
      unsigned pos = base + (unsigned)__popcll(m & ((1ull << lane) - 1ull));
      Edge e; e.j = (unsigned)j; e.w = s * di * Dis[j];
      edges[pos] = e;
    }
    base += (unsigned)__popcll(m);
  }
}

// ------- Chebyshev state init — r11 verbatim -------
__global__ __launch_bounds__(256) void init_k(const int* __restrict__ lab,
                                              const int* __restrict__ labflag,
                                              float2* __restrict__ x,
                                              float2* __restrict__ r,
                                              float2* __restrict__ d) {
  const int m = blockIdx.x * 256 + threadIdx.x;
  const int isI64 = labflag[0];
  float2 b = make_float2(0.0f, 0.0f);
  if (m < N_LAB) {
    int c = isI64 ? lab[2 * m] : lab[m];
    b.x = (c == 0) ? 1.0f : 0.0f;
    b.y = (c == 1) ? 1.0f : 0.0f;
  }
  x[m] = make_float2(0.0f, 0.0f);
  r[m] = b;
  d[m] = b;
}

// ---- one Chebyshev iteration — r11 verbatim ----
__global__ __launch_bounds__(512) void chebit_k(const Edge* __restrict__ edges,
                                                const unsigned* __restrict__ rowPtr,
                                                const float2* __restrict__ dIn,
                                                float2* __restrict__ dOut,
                                                float2* __restrict__ x,
                                                float2* __restrict__ r,
                                                float c1, float c2, int last) {
  const int row = blockIdx.x * 8 + (threadIdx.x >> 6);
  const int lane = threadIdx.x & 63;
  const unsigned b0 = rowPtr[row], b1 = rowPtr[row + 1];
  float ax = 0.0f, ay = 0.0f;
  for (unsigned e = b0 + lane; e < b1; e += 64) {
    Edge ed = edges[e];
    float2 dj = dIn[ed.j];
    ax += ed.w * dj.x;
    ay += ed.w * dj.y;
  }
#pragma unroll
  for (int d = 32; d >= 1; d >>= 1) {
    ax += __shfl_xor(ax, d);
    ay += __shfl_xor(ay, d);
  }
  if (lane == 0) {
    float2 di = dIn[row], xi = x[row], ri = r[row];
    xi.x += di.x; xi.y += di.y;
    ri.x += ALPHA_ * ax - di.x;
    ri.y += ALPHA_ * ay - di.y;
    x[row] = xi;
    r[row] = ri;
    if (!last) {
      float2 dn;
      dn.x = c1 * di.x + c2 * ri.x;
      dn.y = c1 * di.y + c2 * ri.y;
      dOut[row] = dn;
    }
  }
}

// ------- emit queries — r11 verbatim -------
__global__ __launch_bounds__(256) void out_k(const float2* __restrict__ x,
                                             float2* __restrict__ out) {
  const int q = blockIdx.x * 256 + threadIdx.x;
  out[q] = x[N_LAB + q];
}

// ---------------- launch ----------------
extern "C" void kernel_launch(void* const* d_in, const int* in_sizes, int n_in,
                              void* d_out, int out_size, void* d_ws, size_t ws_size,
                              hipStream_t stream) {
  int iL = 0, iT = 1, iU = 2;
  for (int i = 0; i < n_in; ++i) {
    if (in_sizes[i] == N_LAB * DIMF) iL = i;
    else if (in_sizes[i] == (N_ALL - N_LAB) * DIMF) iU = i;
    else iT = i;
  }
  const float* L = (const float*)d_in[iL];
  const int* lab = (const int*)d_in[iT];
  const float* U = (const float*)d_in[iU];
  float2* out = (float2*)d_out;

  char* w = (char*)d_ws;
  size_t off = 0;
  auto alloc = [&](size_t bytes) {
    void* p = (void*)(w + off);
    off += (bytes + 255) & ~(size_t)255;
    return p;
  };
  float* W = (float*)alloc((size_t)N_ALL * N_ALL * 4);       // 64 MB
  double* sqd = (double*)alloc(N_ALL * 8);
  unsigned* t4i = (unsigned*)alloc(N_ALL * 4 * 4);
  float* Dis = (float*)alloc(N_ALL * 4);
  unsigned* nn = (unsigned*)alloc(N_ALL * 4);
  unsigned* rowPtr = (unsigned*)alloc((N_ALL + 1) * 4);
  int* labflag = (int*)alloc(256);
  Edge* edges = (Edge*)alloc((size_t)EDGECAP * sizeof(Edge));  // 256 KB
  float2* xv = (float2*)alloc(N_ALL * 8);
  float2* rv = (float2*)alloc(N_ALL * 8);
  float2* dv0 = (float2*)alloc(N_ALL * 8);
  float2* dv1 = (float2*)alloc(N_ALL * 8);
  if (off > ws_size) return;

  labfmt_k<<<1, 256, 0, stream>>>(lab, labflag);
  sqd_k<<<N_ALL, 256, 0, stream>>>(L, U, sqd);
  gram_k<<<dim3(128, 128), dim3(16, 16), 0, stream>>>(L, U, sqd, W);
  top4_k<<<N_ALL / 4, 256, 0, stream>>>(W, t4i);
  maskD_k<<<N_ALL, 256, 0, stream>>>(t4i, W, Dis, nn);
  scanP_k<<<1, 64, 0, stream>>>(nn, rowPtr);
  fillcsr_k<<<N_ALL / 4, 256, 0, stream>>>(W, Dis, rowPtr, edges);
  init_k<<<N_ALL / 256, 256, 0, stream>>>(lab, labflag, xv, rv, dv0);

  const double theta = 1.0, delta = 0.992;
  const double sigma1 = theta / delta;
  double rho = delta / theta;
  float2* dA = dv0;
  float2* dB = dv1;
  for (int k = 0; k < NIT_CH; ++k) {
    const int last = (k == NIT_CH - 1);
    const double rho_new = 1.0 / (2.0 * sigma1 - rho);
    const float c1 = (float)(rho_new * rho);
    const float c2 = (float)(2.0 * rho_new / delta);
    chebit_k<<<N_ALL / 8, 512, 0, stream>>>(edges, rowPtr, dA, dB, xv, rv,
                                            c1, c2, last);
    rho = rho_new;
    float2* t = dA; dA = dB; dB = t;
  }
  out_k<<<(N_ALL - N_LAB) / 256, 256, 0, stream>>>(xv, out);
}

// Round 13
// 1309.465 us; speedup vs baseline: 10.1907x; 1.1064x over previous
//
#include <hip/hip_runtime.h>

#define N_ALL 4096
#define N_LAB 1024
#define DIMF 1024
#define EDGECAP 32768
#define ALPHA_ 0.99f
#define NIT_CH 120
#define EPS_D 2.220446049250313e-16

struct __align__(8) Edge { unsigned j; float w; };

__device__ inline const float* xrow(const float* L, const float* U, int r) {
  return (r < N_LAB) ? (L + (size_t)r * DIMF) : (U + (size_t)(r - N_LAB) * DIMF);
}

// ------- label-layout probe — r12 verbatim -------
__global__ __launch_bounds__(256) void labfmt_k(const int* __restrict__ lab,
                                                int* __restrict__ flag) {
  const long long* l64 = (const long long*)lab;
  int bad = 0;
  for (int k = threadIdx.x; k < 512; k += 256) {
    long long v = l64[k];
    if (v != 0 && v != 1) bad = 1;
  }
  __shared__ int sbad[4];
  unsigned long long m = __ballot(bad);
  if ((threadIdx.x & 63) == 0) sbad[threadIdx.x >> 6] = (m != 0ull);
  __syncthreads();
  if (threadIdx.x == 0)
    flag[0] = (sbad[0] | sbad[1] | sbad[2] | sbad[3]) ? 0 : 1;
}

// ---------------- row squared norms (fp64) — r12 verbatim ----------------
__global__ __launch_bounds__(256) void sqd_k(const float* __restrict__ L,
                                             const float* __restrict__ U,
                                             double* __restrict__ sqd) {
  const int row = blockIdx.x;
  const int tid = threadIdx.x;
  const float* src = xrow(L, U, row);
  float4 v = ((const float4*)src)[tid];
  double s = (double)v.x * v.x + (double)v.y * v.y +
             (double)v.z * v.z + (double)v.w * v.w;
#pragma unroll
  for (int d = 32; d >= 1; d >>= 1) s += __shfl_xor(s, d);
  __shared__ double wsum[4];
  if ((tid & 63) == 0) wsum[tid >> 6] = s;
  __syncthreads();
  if (tid == 0) sqd[row] = wsum[0] + wsum[1] + wsum[2] + wsum[3];
}

// ------- dense Gram fp64 -> W; 64x64 tile, 4x4/thread; upper tri + mirror -------
// Per-(i,j) accumulation: ascending k, same `acc += (double)a*b` expression as
// r12 => same fma contraction & order => bitwise-identical W.
__global__ __launch_bounds__(256) void gram_k(const float* __restrict__ L,
                                              const float* __restrict__ U,
                                              const double* __restrict__ sqd,
                                              float* __restrict__ W) {
  if (blockIdx.y > blockIdx.x) return;  // lower-triangle blocks mirrored instead
  __shared__ float As[64][20], Bs[64][20];  // 80 B rows: b128-aligned, 2-way banks
  const int tid = threadIdx.x;
  const int tx = tid & 15, ty = tid >> 4;
  const int br = blockIdx.y * 64, bc = blockIdx.x * 64;
  const int lr = tid >> 2;           // 0..63
  const int lc = (tid & 3) * 4;      // 0,4,8,12
  const float* ga = xrow(L, U, br + lr);
  const float* gb = xrow(L, U, bc + lr);
  double acc[4][4] = {};
  for (int k0 = 0; k0 < DIMF; k0 += 16) {
    float4 va = *(const float4*)(ga + k0 + lc);
    float4 vb = *(const float4*)(gb + k0 + lc);
    __syncthreads();
    *(float4*)&As[lr][lc] = va;
    *(float4*)&Bs[lr][lc] = vb;
    __syncthreads();
#pragma unroll
    for (int kk = 0; kk < 4; ++kk) {
      float4 a[4], b[4];
#pragma unroll
      for (int ii = 0; ii < 4; ++ii) a[ii] = *(const float4*)&As[ty + 16 * ii][kk * 4];
#pragma unroll
      for (int jj = 0; jj < 4; ++jj) b[jj] = *(const float4*)&Bs[tx + 16 * jj][kk * 4];
#pragma unroll
      for (int ii = 0; ii < 4; ++ii)
#pragma unroll
        for (int jj = 0; jj < 4; ++jj) {
          acc[ii][jj] += (double)a[ii].x * b[jj].x;
          acc[ii][jj] += (double)a[ii].y * b[jj].y;
          acc[ii][jj] += (double)a[ii].z * b[jj].z;
          acc[ii][jj] += (double)a[ii].w * b[jj].w;
        }
    }
  }
#pragma unroll
  for (int ii = 0; ii < 4; ++ii) {
    const int r = br + ty + 16 * ii;
    const double sr = sqd[r];
#pragma unroll
    for (int jj = 0; jj < 4; ++jj) {
      const int c = bc + tx + 16 * jj;
      double dist = (sr + sqd[c] - 2.0 * acc[ii][jj]) * (1.0 / 1024.0);
      float wv = (r == c) ? 0.0f : (float)exp(-0.5 * dist);
      W[(size_t)r * N_ALL + c] = wv;
      W[(size_t)c * N_ALL + r] = wv;  // mirror: acc & sq-sum commute -> bitwise
    }
  }
}

// ------- exact top-4 per row, single scan; identical output to r12's 4-scan -------
// Per-lane top-8 buffer over its 64-item stream, then 4 wave-argmax rounds with
// key (val_bits, ~j). Any item dropped from a full buffer ties >=8 kept items
// of lower j, so it could never enter the (val, lower-j)-ordered top-4.
__global__ __launch_bounds__(256) void top4_k(const float* __restrict__ W,
                                              unsigned* __restrict__ t4i) {
  const int wave = threadIdx.x >> 6, lane = threadIdx.x & 63;
  const int row = blockIdx.x * 4 + wave;
  const float* Wr = W + (size_t)row * N_ALL;
  float bv[8]; unsigned bj[8];
#pragma unroll
  for (int t = 0; t < 8; ++t) { bv[t] = -1.0f; bj[t] = 0xFFFFFFFFu; }
  float minv = -1.0f; int mins = 0;
  for (int s = 0; s < 64; ++s) {
    int j = s * 64 + lane;
    float v = Wr[j];
    if (v > minv) {
#pragma unroll
      for (int t = 0; t < 8; ++t) if (t == mins) { bv[t] = v; bj[t] = (unsigned)j; }
      minv = bv[0]; mins = 0;
#pragma unroll
      for (int t = 1; t < 8; ++t) if (bv[t] < minv) { minv = bv[t]; mins = t; }
    }
  }
  for (int pick = 0; pick < 4; ++pick) {
    unsigned long long best = 0;
#pragma unroll
    for (int t = 0; t < 8; ++t) {
      bool valid = (bv[t] >= 0.0f);
      unsigned long long key =
          ((unsigned long long)__float_as_uint(bv[t]) << 32) |
          (unsigned long long)(0xFFFFFFFFu - bj[t]);
      if (valid && key > best) best = key;
    }
#pragma unroll
    for (int d = 32; d >= 1; d >>= 1) {
      unsigned long long o = __shfl_xor(best, d);
      if (o > best) best = o;
    }
    unsigned wj = 0xFFFFFFFFu - (unsigned)(best & 0xFFFFFFFFull);
    if (lane == 0) t4i[row * 4 + pick] = wj;
#pragma unroll
    for (int t = 0; t < 8; ++t) if (bj[t] == wj) bv[t] = -1.0f;
  }
}

// ------- dense mask (in place) + f64 row sums -> Dis + keep-count — r12 verbatim -------
__global__ __launch_bounds__(256) void maskD_k(const unsigned* __restrict__ t4i,
                                               float* __restrict__ W,
                                               float* __restrict__ Dis,
                                               unsigned* __restrict__ nn) {
  const int i = blockIdx.x;
  const int tid = threadIdx.x;
  const uint4 mine = ((const uint4*)t4i)[i];
  float* Wr = W + (size_t)i * N_ALL;
  double ds = 0.0;
  int kc = 0;
  for (int s = 0; s < 16; ++s) {
    int j = tid + 256 * s;
    uint4 tj = ((const uint4*)t4i)[j];
    bool keep = (mine.x == (unsigned)j) | (mine.y == (unsigned)j) |
                (mine.z == (unsigned)j) | (mine.w == (unsigned)j) |
                (tj.x == (unsigned)i) | (tj.y == (unsigned)i) |
                (tj.z == (unsigned)i) | (tj.w == (unsigned)i);
    keep = keep && (j != i);
    float w = keep ? Wr[j] : 0.0f;
    Wr[j] = w;
    ds += (double)w;
    kc += keep ? 1 : 0;
  }
#pragma unroll
  for (int d = 32; d >= 1; d >>= 1) {
    ds += __shfl_xor(ds, d);
    kc += __shfl_xor(kc, d);
  }
  __shared__ double scr[4];
  __shared__ int scc[4];
  if ((tid & 63) == 0) { scr[tid >> 6] = ds; scc[tid >> 6] = kc; }
  __syncthreads();
  if (tid == 0) {
    double D = scr[0] + scr[1] + scr[2] + scr[3];
    Dis[i] = (float)sqrt(1.0 / (D + EPS_D));
    nn[i] = (unsigned)(scc[0] + scc[1] + scc[2] + scc[3]);
  }
}

// ------- exclusive scan of nn -> CSR rowPtr — r12 verbatim -------
__global__ __launch_bounds__(64) void scanP_k(const unsigned* __restrict__ nn,
                                              unsigned* __restrict__ rowPtr) {
  const int lane = threadIdx.x;
  unsigned running = 0;
  for (int j0 = 0; j0 < N_ALL; j0 += 64) {
    int v = (int)nn[j0 + lane];
    int incl = v;
#pragma unroll
    for (int d = 1; d < 64; d <<= 1) {
      int t = __shfl_up(incl, d);
      if (lane >= d) incl += t;
    }
    rowPtr[j0 + lane] = running + (unsigned)(incl - v);
    running += (unsigned)__shfl(incl, 63);
  }
  if (lane == 0) rowPtr[N_ALL] = running;
}

// ------- CSR fill from masked W with inline scaling — r12 verbatim -------
__global__ __launch_bounds__(256) void fillcsr_k(const float* __restrict__ Wm,
                                                 const float* __restrict__ Dis,
                                                 const unsigned* __restrict__ rowPtr,
                                                 Edge* __restrict__ edges) {
  const int wave = threadIdx.x >> 6, lane = threadIdx.x & 63;
  const int i = blockIdx.x * 4 + wave;
  const float* Wr = Wm + (size_t)i * N_ALL;
  const float di = Dis[i];
  unsigned base = rowPtr[i];
  for (int j0 = 0; j0 < N_ALL; j0 += 64) {
    int j = j0 + lane;
    float s = Wr[j];
    bool keep = (s != 0.0f);
    unsigned long long m = __ballot(keep);
    if (keep) {
      unsigned pos = base + (unsigned)__popcll(m & ((1ull << lane) - 1ull));
      Edge e; e.j = (unsigned)j; e.w = s * di * Dis[j];
      edges[pos] = e;
    }
    base += (unsigned)__popcll(m);
  }
}

// ------- Chebyshev state init — r12 verbatim -------
__global__ __launch_bounds__(256) void init_k(const int* __restrict__ lab,
                                              const int* __restrict__ labflag,
                                              float2* __restrict__ x,
                                              float2* __restrict__ r,
                                              float2* __restrict__ d) {
  const int m = blockIdx.x * 256 + threadIdx.x;
  const int isI64 = labflag[0];
  float2 b = make_float2(0.0f, 0.0f);
  if (m < N_LAB) {
    int c = isI64 ? lab[2 * m] : lab[m];
    b.x = (c == 0) ? 1.0f : 0.0f;
    b.y = (c == 1) ? 1.0f : 0.0f;
  }
  x[m] = make_float2(0.0f, 0.0f);
  r[m] = b;
  d[m] = b;
}

// ---- one Chebyshev iteration — r12 verbatim ----
__global__ __launch_bounds__(512) void chebit_k(const Edge* __restrict__ edges,
                                                const unsigned* __restrict__ rowPtr,
                                                const float2* __restrict__ dIn,
                                                float2* __restrict__ dOut,
                                                float2* __restrict__ x,
                                                float2* __restrict__ r,
                                                float c1, float c2, int last) {
  const int row = blockIdx.x * 8 + (threadIdx.x >> 6);
  const int lane = threadIdx.x & 63;
  const unsigned b0 = rowPtr[row], b1 = rowPtr[row + 1];
  float ax = 0.0f, ay = 0.0f;
  for (unsigned e = b0 + lane; e < b1; e += 64) {
    Edge ed = edges[e];
    float2 dj = dIn[ed.j];
    ax += ed.w * dj.x;
    ay += ed.w * dj.y;
  }
#pragma unroll
  for (int d = 32; d >= 1; d >>= 1) {
    ax += __shfl_xor(ax, d);
    ay += __shfl_xor(ay, d);
  }
  if (lane == 0) {
    float2 di = dIn[row], xi = x[row], ri = r[row];
    xi.x += di.x; xi.y += di.y;
    ri.x += ALPHA_ * ax - di.x;
    ri.y += ALPHA_ * ay - di.y;
    x[row] = xi;
    r[row] = ri;
    if (!last) {
      float2 dn;
      dn.x = c1 * di.x + c2 * ri.x;
      dn.y = c1 * di.y + c2 * ri.y;
      dOut[row] = dn;
    }
  }
}

// ------- emit queries — r12 verbatim -------
__global__ __launch_bounds__(256) void out_k(const float2* __restrict__ x,
                                             float2* __restrict__ out) {
  const int q = blockIdx.x * 256 + threadIdx.x;
  out[q] = x[N_LAB + q];
}

// ---------------- launch ----------------
extern "C" void kernel_launch(void* const* d_in, const int* in_sizes, int n_in,
                              void* d_out, int out_size, void* d_ws, size_t ws_size,
                              hipStream_t stream) {
  int iL = 0, iT = 1, iU = 2;
  for (int i = 0; i < n_in; ++i) {
    if (in_sizes[i] == N_LAB * DIMF) iL = i;
    else if (in_sizes[i] == (N_ALL - N_LAB) * DIMF) iU = i;
    else iT = i;
  }
  const float* L = (const float*)d_in[iL];
  const int* lab = (const int*)d_in[iT];
  const float* U = (const float*)d_in[iU];
  float2* out = (float2*)d_out;

  char* w = (char*)d_ws;
  size_t off = 0;
  auto alloc = [&](size_t bytes) {
    void* p = (void*)(w + off);
    off += (bytes + 255) & ~(size_t)255;
    return p;
  };
  float* W = (float*)alloc((size_t)N_ALL * N_ALL * 4);       // 64 MB
  double* sqd = (double*)alloc(N_ALL * 8);
  unsigned* t4i = (unsigned*)alloc(N_ALL * 4 * 4);
  float* Dis = (float*)alloc(N_ALL * 4);
  unsigned* nn = (unsigned*)alloc(N_ALL * 4);
  unsigned* rowPtr = (unsigned*)alloc((N_ALL + 1) * 4);
  int* labflag = (int*)alloc(256);
  Edge* edges = (Edge*)alloc((size_t)EDGECAP * sizeof(Edge));  // 256 KB
  float2* xv = (float2*)alloc(N_ALL * 8);
  float2* rv = (float2*)alloc(N_ALL * 8);
  float2* dv0 = (float2*)alloc(N_ALL * 8);
  float2* dv1 = (float2*)alloc(N_ALL * 8);
  if (off > ws_size) return;

  labfmt_k<<<1, 256, 0, stream>>>(lab, labflag);
  sqd_k<<<N_ALL, 256, 0, stream>>>(L, U, sqd);
  gram_k<<<dim3(64, 64), 256, 0, stream>>>(L, U, sqd, W);
  top4_k<<<N_ALL / 4, 256, 0, stream>>>(W, t4i);
  maskD_k<<<N_ALL, 256, 0, stream>>>(t4i, W, Dis, nn);
  scanP_k<<<1, 64, 0, stream>>>(nn, rowPtr);
  fillcsr_k<<<N_ALL / 4, 256, 0, stream>>>(W, Dis, rowPtr, edges);
  init_k<<<N_ALL / 256, 256, 0, stream>>>(lab, labflag, xv, rv, dv0);

  const double theta = 1.0, delta = 0.992;
  const double sigma1 = theta / delta;
  double rho = delta / theta;
  float2* dA = dv0;
  float2* dB = dv1;
  for (int k = 0; k < NIT_CH; ++k) {
    const int last = (k == NIT_CH - 1);
    const double rho_new = 1.0 / (2.0 * sigma1 - rho);
    const float c1 = (float)(rho_new * rho);
    const float c2 = (float)(2.0 * rho_new / delta);
    chebit_k<<<N_ALL / 8, 512, 0, stream>>>(edges, rowPtr, dA, dB, xv, rv,
                                            c1, c2, last);
    rho = rho_new;
    float2* t = dA; dA = dB; dB = t;
  }
  out_k<<<(N_ALL - N_LAB) / 256, 256, 0, stream>>>(xv, out);
}

// Round 14
// 996.322 us; speedup vs baseline: 13.3936x; 1.3143x over previous
//
#include <hip/hip_runtime.h>

#define N_ALL 4096
#define N_LAB 1024
#define DIMF 1024
#define EDGECAP 32768
#define ALPHA_ 0.99f
#define NIT_CH 100
#define EPS_D 2.220446049250313e-16

struct __align__(8) Edge { unsigned j; float w; };

__device__ inline const float* xrow(const float* L, const float* U, int r) {
  return (r < N_LAB) ? (L + (size_t)r * DIMF) : (U + (size_t)(r - N_LAB) * DIMF);
}

// ------- label-layout probe — r13 verbatim -------
__global__ __launch_bounds__(256) void labfmt_k(const int* __restrict__ lab,
                                                int* __restrict__ flag) {
  const long long* l64 = (const long long*)lab;
  int bad = 0;
  for (int k = threadIdx.x; k < 512; k += 256) {
    long long v = l64[k];
    if (v != 0 && v != 1) bad = 1;
  }
  __shared__ int sbad[4];
  unsigned long long m = __ballot(bad);
  if ((threadIdx.x & 63) == 0) sbad[threadIdx.x >> 6] = (m != 0ull);
  __syncthreads();
  if (threadIdx.x == 0)
    flag[0] = (sbad[0] | sbad[1] | sbad[2] | sbad[3]) ? 0 : 1;
}

// ---------------- row squared norms (fp64) — r13 verbatim ----------------
__global__ __launch_bounds__(256) void sqd_k(const float* __restrict__ L,
                                             const float* __restrict__ U,
                                             double* __restrict__ sqd) {
  const int row = blockIdx.x;
  const int tid = threadIdx.x;
  const float* src = xrow(L, U, row);
  float4 v = ((const float4*)src)[tid];
  double s = (double)v.x * v.x + (double)v.y * v.y +
             (double)v.z * v.z + (double)v.w * v.w;
#pragma unroll
  for (int d = 32; d >= 1; d >>= 1) s += __shfl_xor(s, d);
  __shared__ double wsum[4];
  if ((tid & 63) == 0) wsum[tid >> 6] = s;
  __syncthreads();
  if (tid == 0) sqd[row] = wsum[0] + wsum[1] + wsum[2] + wsum[3];
}

// ------- dense Gram FP32 -> W f32; 64x64 tile, 4x4/thread, k0=32 chunks -------
// fp32 values are used for edge weights/degrees (noise budget ~0.01 on output);
// RANKING is protected separately by the fp64 rerank of top-8 candidates.
__global__ __launch_bounds__(256) void gram_k(const float* __restrict__ L,
                                              const float* __restrict__ U,
                                              const double* __restrict__ sqd,
                                              float* __restrict__ W) {
  if (blockIdx.y > blockIdx.x) return;  // upper triangle only + mirror
  __shared__ float As[64][36], Bs[64][36];  // 144 B rows: b128-aligned
  const int tid = threadIdx.x;
  const int tx = tid & 15, ty = tid >> 4;
  const int br = blockIdx.y * 64, bc = blockIdx.x * 64;
  const int lr = tid >> 2;            // 0..63
  const int lc = (tid & 3) * 8;       // 0,8,16,24
  const float* ga = xrow(L, U, br + lr);
  const float* gb = xrow(L, U, bc + lr);
  float acc[4][4] = {};
  for (int k0 = 0; k0 < DIMF; k0 += 32) {
    float4 va0 = *(const float4*)(ga + k0 + lc);
    float4 va1 = *(const float4*)(ga + k0 + lc + 4);
    float4 vb0 = *(const float4*)(gb + k0 + lc);
    float4 vb1 = *(const float4*)(gb + k0 + lc + 4);
    __syncthreads();
    *(float4*)&As[lr][lc] = va0;
    *(float4*)&As[lr][lc + 4] = va1;
    *(float4*)&Bs[lr][lc] = vb0;
    *(float4*)&Bs[lr][lc + 4] = vb1;
    __syncthreads();
#pragma unroll
    for (int kk = 0; kk < 8; ++kk) {
      float4 a[4], b[4];
#pragma unroll
      for (int ii = 0; ii < 4; ++ii) a[ii] = *(const float4*)&As[ty + 16 * ii][kk * 4];
#pragma unroll
      for (int jj = 0; jj < 4; ++jj) b[jj] = *(const float4*)&Bs[tx + 16 * jj][kk * 4];
#pragma unroll
      for (int ii = 0; ii < 4; ++ii)
#pragma unroll
        for (int jj = 0; jj < 4; ++jj) {
          acc[ii][jj] += a[ii].x * b[jj].x;
          acc[ii][jj] += a[ii].y * b[jj].y;
          acc[ii][jj] += a[ii].z * b[jj].z;
          acc[ii][jj] += a[ii].w * b[jj].w;
        }
    }
  }
#pragma unroll
  for (int ii = 0; ii < 4; ++ii) {
    const int r = br + ty + 16 * ii;
    const double sr = sqd[r];
#pragma unroll
    for (int jj = 0; jj < 4; ++jj) {
      const int c = bc + tx + 16 * jj;
      double dist = (sr + sqd[c] - 2.0 * (double)acc[ii][jj]) * (1.0 / 1024.0);
      float wv = (r == c) ? 0.0f : (float)exp(-0.5 * dist);
      W[(size_t)r * N_ALL + c] = wv;
      W[(size_t)c * N_ALL + r] = wv;  // Gram symmetric: mirror store
    }
  }
}

// ------- top-8 candidates per row (fp32 W), single scan -------
__global__ __launch_bounds__(256) void top8_k(const float* __restrict__ W,
                                              unsigned* __restrict__ t8i) {
  const int wave = threadIdx.x >> 6, lane = threadIdx.x & 63;
  const int row = blockIdx.x * 4 + wave;
  const float* Wr = W + (size_t)row * N_ALL;
  float bv[8]; unsigned bj[8];
#pragma unroll
  for (int t = 0; t < 8; ++t) { bv[t] = -1.0f; bj[t] = 0xFFFFFFFFu; }
  float minv = -1.0f; int mins = 0;
  for (int s = 0; s < 64; ++s) {
    int j = s * 64 + lane;
    float v = Wr[j];
    if (v > minv) {
#pragma unroll
      for (int t = 0; t < 8; ++t) if (t == mins) { bv[t] = v; bj[t] = (unsigned)j; }
      minv = bv[0]; mins = 0;
#pragma unroll
      for (int t = 1; t < 8; ++t) if (bv[t] < minv) { minv = bv[t]; mins = t; }
    }
  }
  for (int pick = 0; pick < 8; ++pick) {
    unsigned long long best = 0;
#pragma unroll
    for (int t = 0; t < 8; ++t) {
      bool valid = (bv[t] >= 0.0f);
      unsigned long long key =
          ((unsigned long long)__float_as_uint(bv[t]) << 32) |
          (unsigned long long)(0xFFFFFFFFu - bj[t]);
      if (valid && key > best) best = key;
    }
#pragma unroll
    for (int d = 32; d >= 1; d >>= 1) {
      unsigned long long o = __shfl_xor(best, d);
      if (o > best) best = o;
    }
    unsigned wj = 0xFFFFFFFFu - (unsigned)(best & 0xFFFFFFFFull);
    if (lane == 0) t8i[row * 8 + pick] = wj;
#pragma unroll
    for (int t = 0; t < 8; ++t) if (bj[t] == wj) bv[t] = -1.0f;
  }
}

// ------- fp64-exact rerank of the 8 candidates -> exact top-4 indices -------
// Products of fp32 inputs are exact in fp64; dot error ~1e-14 vs rank gaps
// ~1e-2 => ranking matches the np-f64 reference. Tie-break: lower index.
__global__ __launch_bounds__(256) void rerank_k(const float* __restrict__ L,
                                                const float* __restrict__ U,
                                                const double* __restrict__ sqd,
                                                const unsigned* __restrict__ t8i,
                                                unsigned* __restrict__ t4i) {
  const int wave = threadIdx.x >> 6, lane = threadIdx.x & 63;
  const int row = blockIdx.x * 4 + wave;
  const float* xi = xrow(L, U, row);
  float xr[16];
#pragma unroll
  for (int t = 0; t < 16; ++t) xr[t] = xi[t * 64 + lane];
  unsigned cj[8];
  double cw[8];
#pragma unroll
  for (int c = 0; c < 8; ++c) cj[c] = t8i[row * 8 + c];
  for (int c = 0; c < 8; ++c) {
    const float* xj = xrow(L, U, (int)cj[c]);
    double s = 0.0;
#pragma unroll
    for (int t = 0; t < 16; ++t) s += (double)xr[t] * xj[t * 64 + lane];
#pragma unroll
    for (int d = 32; d >= 1; d >>= 1) s += __shfl_xor(s, d);
    double dist = (sqd[row] + sqd[cj[c]] - 2.0 * s) * (1.0 / 1024.0);
    cw[c] = exp(-0.5 * dist);
  }
  if (lane == 0) {
#pragma unroll
    for (int pick = 0; pick < 4; ++pick) {
      int ms = -1;
      double mv = -1.0;
      unsigned mj = 0xFFFFFFFFu;
#pragma unroll
      for (int c = 0; c < 8; ++c) {
        bool better = (cw[c] > mv) || (cw[c] == mv && cj[c] < mj);
        if (cw[c] >= 0.0 && better) { mv = cw[c]; mj = cj[c]; ms = c; }
      }
      t4i[row * 4 + pick] = mj;
      cw[ms] = -2.0;
    }
  }
}

// ------- dense mask (in place) + f64 row sums -> Dis + keep-count — r13 verbatim -------
__global__ __launch_bounds__(256) void maskD_k(const unsigned* __restrict__ t4i,
                                               float* __restrict__ W,
                                               float* __restrict__ Dis,
                                               unsigned* __restrict__ nn) {
  const int i = blockIdx.x;
  const int tid = threadIdx.x;
  const uint4 mine = ((const uint4*)t4i)[i];
  float* Wr = W + (size_t)i * N_ALL;
  double ds = 0.0;
  int kc = 0;
  for (int s = 0; s < 16; ++s) {
    int j = tid + 256 * s;
    uint4 tj = ((const uint4*)t4i)[j];
    bool keep = (mine.x == (unsigned)j) | (mine.y == (unsigned)j) |
                (mine.z == (unsigned)j) | (mine.w == (unsigned)j) |
                (tj.x == (unsigned)i) | (tj.y == (unsigned)i) |
                (tj.z == (unsigned)i) | (tj.w == (unsigned)i);
    keep = keep && (j != i);
    float w = keep ? Wr[j] : 0.0f;
    Wr[j] = w;
    ds += (double)w;
    kc += keep ? 1 : 0;
  }
#pragma unroll
  for (int d = 32; d >= 1; d >>= 1) {
    ds += __shfl_xor(ds, d);
    kc += __shfl_xor(kc, d);
  }
  __shared__ double scr[4];
  __shared__ int scc[4];
  if ((tid & 63) == 0) { scr[tid >> 6] = ds; scc[tid >> 6] = kc; }
  __syncthreads();
  if (tid == 0) {
    double D = scr[0] + scr[1] + scr[2] + scr[3];
    Dis[i] = (float)sqrt(1.0 / (D + EPS_D));
    nn[i] = (unsigned)(scc[0] + scc[1] + scc[2] + scc[3]);
  }
}

// ------- exclusive scan of nn -> CSR rowPtr — r13 verbatim -------
__global__ __launch_bounds__(64) void scanP_k(const unsigned* __restrict__ nn,
                                              unsigned* __restrict__ rowPtr) {
  const int lane = threadIdx.x;
  unsigned running = 0;
  for (int j0 = 0; j0 < N_ALL; j0 += 64) {
    int v = (int)nn[j0 + lane];
    int incl = v;
#pragma unroll
    for (int d = 1; d < 64; d <<= 1) {
      int t = __shfl_up(incl, d);
      if (lane >= d) incl += t;
    }
    rowPtr[j0 + lane] = running + (unsigned)(incl - v);
    running += (unsigned)__shfl(incl, 63);
  }
  if (lane == 0) rowPtr[N_ALL] = running;
}

// ------- CSR fill from masked W with inline scaling — r13 verbatim -------
__global__ __launch_bounds__(256) void fillcsr_k(const float* __restrict__ Wm,
                                                 const float* __restrict__ Dis,
                                                 const unsigned* __restrict__ rowPtr,
                                                 Edge* __restrict__ edges) {
  const int wave = threadIdx.x >> 6, lane = threadIdx.x & 63;
  const int i = blockIdx.x * 4 + wave;
  const float* Wr = Wm + (size_t)i * N_ALL;
  const float di = Dis[i];
  unsigned base = rowPtr[i];
  for (int j0 = 0; j0 < N_ALL; j0 += 64) {
    int j = j0 + lane;
    float s = Wr[j];
    bool keep = (s != 0.0f);
    unsigned long long m = __ballot(keep);
    if (keep) {
      unsigned pos = base + (unsigned)__popcll(m & ((1ull << lane) - 1ull));
      Edge e; e.j = (unsigned)j; e.w = s * di * Dis[j];
      edges[pos] = e;
    }
    base += (unsigned)__popcll(m);
  }
}

// ------- Chebyshev state init — r13 verbatim -------
__global__ __launch_bounds__(256) void init_k(const int* __restrict__ lab,
                                              const int* __restrict__ labflag,
                                              float2* __restrict__ x,
                                              float2* __restrict__ r,
                                              float2* __restrict__ d) {
  const int m = blockIdx.x * 256 + threadIdx.x;
  const int isI64 = labflag[0];
  float2 b = make_float2(0.0f, 0.0f);
  if (m < N_LAB) {
    int c = isI64 ? lab[2 * m] : lab[m];
    b.x = (c == 0) ? 1.0f : 0.0f;
    b.y = (c == 1) ? 1.0f : 0.0f;
  }
  x[m] = make_float2(0.0f, 0.0f);
  r[m] = b;
  d[m] = b;
}

// ---- one Chebyshev iteration — r13 verbatim ----
__global__ __launch_bounds__(512) void chebit_k(const Edge* __restrict__ edges,
                                                const unsigned* __restrict__ rowPtr,
                                                const float2* __restrict__ dIn,
                                                float2* __restrict__ dOut,
                                                float2* __restrict__ x,
                                                float2* __restrict__ r,
                                                float c1, float c2, int last) {
  const int row = blockIdx.x * 8 + (threadIdx.x >> 6);
  const int lane = threadIdx.x & 63;
  const unsigned b0 = rowPtr[row], b1 = rowPtr[row + 1];
  float ax = 0.0f, ay = 0.0f;
  for (unsigned e = b0 + lane; e < b1; e += 64) {
    Edge ed = edges[e];
    float2 dj = dIn[ed.j];
    ax += ed.w * dj.x;
    ay += ed.w * dj.y;
  }
#pragma unroll
  for (int d = 32; d >= 1; d >>= 1) {
    ax += __shfl_xor(ax, d);
    ay += __shfl_xor(ay, d);
  }
  if (lane == 0) {
    float2 di = dIn[row], xi = x[row], ri = r[row];
    xi.x += di.x; xi.y += di.y;
    ri.x += ALPHA_ * ax - di.x;
    ri.y += ALPHA_ * ay - di.y;
    x[row] = xi;
    r[row] = ri;
    if (!last) {
      float2 dn;
      dn.x = c1 * di.x + c2 * ri.x;
      dn.y = c1 * di.y + c2 * ri.y;
      dOut[row] = dn;
    }
  }
}

// ------- emit queries — r13 verbatim -------
__global__ __launch_bounds__(256) void out_k(const float2* __restrict__ x,
                                             float2* __restrict__ out) {
  const int q = blockIdx.x * 256 + threadIdx.x;
  out[q] = x[N_LAB + q];
}

// ---------------- launch ----------------
extern "C" void kernel_launch(void* const* d_in, const int* in_sizes, int n_in,
                              void* d_out, int out_size, void* d_ws, size_t ws_size,
                              hipStream_t stream) {
  int iL = 0, iT = 1, iU = 2;
  for (int i = 0; i < n_in; ++i) {
    if (in_sizes[i] == N_LAB * DIMF) iL = i;
    else if (in_sizes[i] == (N_ALL - N_LAB) * DIMF) iU = i;
    else iT = i;
  }
  const float* L = (const float*)d_in[iL];
  const int* lab = (const int*)d_in[iT];
  const float* U = (const float*)d_in[iU];
  float2* out = (float2*)d_out;

  char* w = (char*)d_ws;
  size_t off = 0;
  auto alloc = [&](size_t bytes) {
    void* p = (void*)(w + off);
    off += (bytes + 255) & ~(size_t)255;
    return p;
  };
  float* W = (float*)alloc((size_t)N_ALL * N_ALL * 4);       // 64 MB
  double* sqd = (double*)alloc(N_ALL * 8);
  unsigned* t8i = (unsigned*)alloc(N_ALL * 8 * 4);
  unsigned* t4i = (unsigned*)alloc(N_ALL * 4 * 4);
  float* Dis = (float*)alloc(N_ALL * 4);
  unsigned* nn = (unsigned*)alloc(N_ALL * 4);
  unsigned* rowPtr = (unsigned*)alloc((N_ALL + 1) * 4);
  int* labflag = (int*)alloc(256);
  Edge* edges = (Edge*)alloc((size_t)EDGECAP * sizeof(Edge));  // 256 KB
  float2* xv = (float2*)alloc(N_ALL * 8);
  float2* rv = (float2*)alloc(N_ALL * 8);
  float2* dv0 = (float2*)alloc(N_ALL * 8);
  float2* dv1 = (float2*)alloc(N_ALL * 8);
  if (off > ws_size) return;

  labfmt_k<<<1, 256, 0, stream>>>(lab, labflag);
  sqd_k<<<N_ALL, 256, 0, stream>>>(L, U, sqd);
  gram_k<<<dim3(64, 64), 256, 0, stream>>>(L, U, sqd, W);
  top8_k<<<N_ALL / 4, 256, 0, stream>>>(W, t8i);
  rerank_k<<<N_ALL / 4, 256, 0, stream>>>(L, U, sqd, t8i, t4i);
  maskD_k<<<N_ALL, 256, 0, stream>>>(t4i, W, Dis, nn);
  scanP_k<<<1, 64, 0, stream>>>(nn, rowPtr);
  fillcsr_k<<<N_ALL / 4, 256, 0, stream>>>(W, Dis, rowPtr, edges);
  init_k<<<N_ALL / 256, 256, 0, stream>>>(lab, labflag, xv, rv, dv0);

  const double theta = 1.0, delta = 0.992;
  const double sigma1 = theta / delta;
  double rho = delta / theta;
  float2* dA = dv0;
  float2* dB = dv1;
  for (int k = 0; k < NIT_CH; ++k) {
    const int last = (k == NIT_CH - 1);
    const double rho_new = 1.0 / (2.0 * sigma1 - rho);
    const float c1 = (float)(rho_new * rho);
    const float c2 = (float)(2.0 * rho_new / delta);
    chebit_k<<<N_ALL / 8, 512, 0, stream>>>(edges, rowPtr, dA, dB, xv, rv,
                                            c1, c2, last);
    rho = rho_new;
    float2* t = dA; dA = dB; dB = t;
  }
  out_k<<<(N_ALL - N_LAB) / 256, 256, 0, stream>>>(xv, out);
}

// Round 15
// 647.296 us; speedup vs baseline: 20.6155x; 1.5392x over previous
//
#include <hip/hip_runtime.h>

#define N_ALL 4096
#define N_LAB 1024
#define DIMF 1024
#define EDGECAP 32768
#define ALPHA_ 0.99f
#define NIT_CH 100
#define EPS_D 2.220446049250313e-16

typedef short bf16x8 __attribute__((ext_vector_type(8)));
typedef float f32x4 __attribute__((ext_vector_type(4)));

struct __align__(8) Edge { unsigned j; float w; };

__device__ inline const float* xrow(const float* L, const float* U, int r) {
  return (r < N_LAB) ? (L + (size_t)r * DIMF) : (U + (size_t)(r - N_LAB) * DIMF);
}

__device__ inline void load_lds16(const void* g, void* l) {
  __builtin_amdgcn_global_load_lds(
      (const __attribute__((address_space(1))) unsigned int*)g,
      (__attribute__((address_space(3))) unsigned int*)l, 16, 0, 0);
}

__device__ inline unsigned short bf16rne(float f) {
  unsigned u = __float_as_uint(f);
  unsigned r = (u + 0x7fffu + ((u >> 16) & 1u)) >> 16;
  return (unsigned short)r;
}

// ------- label-layout probe — r14 verbatim -------
__global__ __launch_bounds__(256) void labfmt_k(const int* __restrict__ lab,
                                                int* __restrict__ flag) {
  const long long* l64 = (const long long*)lab;
  int bad = 0;
  for (int k = threadIdx.x; k < 512; k += 256) {
    long long v = l64[k];
    if (v != 0 && v != 1) bad = 1;
  }
  __shared__ int sbad[4];
  unsigned long long m = __ballot(bad);
  if ((threadIdx.x & 63) == 0) sbad[threadIdx.x >> 6] = (m != 0ull);
  __syncthreads();
  if (threadIdx.x == 0)
    flag[0] = (sbad[0] | sbad[1] | sbad[2] | sbad[3]) ? 0 : 1;
}

// ------- prep: fp32 -> bf16 copy + fp32 & fp64 row norms -------
__global__ __launch_bounds__(256) void prep_k(const float* __restrict__ L,
                                              const float* __restrict__ U,
                                              unsigned short* __restrict__ Xbf,
                                              float* __restrict__ sq,
                                              double* __restrict__ sqd) {
  const int row = blockIdx.x;
  const int tid = threadIdx.x;
  const float* src = xrow(L, U, row);
  float4 v = ((const float4*)src)[tid];
  ushort4 h;
  h.x = bf16rne(v.x); h.y = bf16rne(v.y); h.z = bf16rne(v.z); h.w = bf16rne(v.w);
  ((ushort4*)(Xbf + (size_t)row * DIMF))[tid] = h;
  float s = v.x * v.x + v.y * v.y + v.z * v.z + v.w * v.w;
  double sd = (double)v.x * v.x + (double)v.y * v.y +
              (double)v.z * v.z + (double)v.w * v.w;
#pragma unroll
  for (int d = 32; d >= 1; d >>= 1) {
    s += __shfl_xor(s, d);
    sd += __shfl_xor(sd, d);
  }
  __shared__ float wsum[4];
  __shared__ double wsumd[4];
  if ((tid & 63) == 0) { wsum[tid >> 6] = s; wsumd[tid >> 6] = sd; }
  __syncthreads();
  if (tid == 0) {
    sq[row] = wsum[0] + wsum[1] + wsum[2] + wsum[3];
    sqd[row] = wsumd[0] + wsumd[1] + wsumd[2] + wsumd[3];
  }
}

// ------- MFMA bf16 gram -> W fp32 (CANDIDATE values only; diag zeroed) -------
// 128x128 tile, 16x16x32 MFMA, global_load_lds width-16 staging (r1 structure).
__global__ __launch_bounds__(256) void gemm_w(const unsigned short* __restrict__ Xbf,
                                              const float* __restrict__ sq,
                                              float* __restrict__ W) {
  __shared__ unsigned short At[128 * 32];
  __shared__ unsigned short Bt[128 * 32];
  const int tid = threadIdx.x;
  const int wave = tid >> 6, lane = tid & 63;
  const int brow = blockIdx.y * 128, bcol = blockIdx.x * 128;
  const int q = lane >> 4, rl = lane & 15;
  const int wr = (wave >> 1) * 64, wc = (wave & 1) * 64;

  f32x4 acc[4][4] = {};

  const int srow = tid >> 2;
  const int soff = (tid & 3) * 8;

  for (int k0 = 0; k0 < DIMF; k0 += 32) {
#pragma unroll
    for (int half = 0; half < 2; ++half) {
      const unsigned short* ga =
          Xbf + (size_t)(brow + half * 64 + srow) * DIMF + k0 + soff;
      load_lds16(ga, &At[(half * 64 + wave * 16) * 32]);
      const unsigned short* gb =
          Xbf + (size_t)(bcol + half * 64 + srow) * DIMF + k0 + soff;
      load_lds16(gb, &Bt[(half * 64 + wave * 16) * 32]);
    }
    __syncthreads();
    bf16x8 af[4], bf_[4];
#pragma unroll
    for (int t = 0; t < 4; ++t) {
      af[t] = *(const bf16x8*)&At[(wr + t * 16 + rl) * 32 + q * 8];
      bf_[t] = *(const bf16x8*)&Bt[(wc + t * 16 + rl) * 32 + q * 8];
    }
#pragma unroll
    for (int i = 0; i < 4; ++i)
#pragma unroll
      for (int j = 0; j < 4; ++j)
        acc[i][j] = __builtin_amdgcn_mfma_f32_16x16x32_bf16(af[i], bf_[j], acc[i][j], 0, 0, 0);
    __syncthreads();
  }

#pragma unroll
  for (int i = 0; i < 4; ++i) {
#pragma unroll
    for (int j = 0; j < 4; ++j) {
#pragma unroll
      for (int reg = 0; reg < 4; ++reg) {
        int gr = brow + wr + i * 16 + q * 4 + reg;
        int gc = bcol + wc + j * 16 + rl;
        float g = acc[i][j][reg];
        float dist = (sq[gr] + sq[gc] - 2.0f * g) * (1.0f / 1024.0f);
        float w = expf(-0.5f * dist);
        if (gr == gc) w = 0.0f;
        W[(size_t)gr * N_ALL + gc] = w;
      }
    }
  }
}

// ------- top-8 candidates per row — r14 verbatim -------
__global__ __launch_bounds__(256) void top8_k(const float* __restrict__ W,
                                              unsigned* __restrict__ t8i) {
  const int wave = threadIdx.x >> 6, lane = threadIdx.x & 63;
  const int row = blockIdx.x * 4 + wave;
  const float* Wr = W + (size_t)row * N_ALL;
  float bv[8]; unsigned bj[8];
#pragma unroll
  for (int t = 0; t < 8; ++t) { bv[t] = -1.0f; bj[t] = 0xFFFFFFFFu; }
  float minv = -1.0f; int mins = 0;
  for (int s = 0; s < 64; ++s) {
    int j = s * 64 + lane;
    float v = Wr[j];
    if (v > minv) {
#pragma unroll
      for (int t = 0; t < 8; ++t) if (t == mins) { bv[t] = v; bj[t] = (unsigned)j; }
      minv = bv[0]; mins = 0;
#pragma unroll
      for (int t = 1; t < 8; ++t) if (bv[t] < minv) { minv = bv[t]; mins = t; }
    }
  }
  for (int pick = 0; pick < 8; ++pick) {
    unsigned long long best = 0;
#pragma unroll
    for (int t = 0; t < 8; ++t) {
      bool valid = (bv[t] >= 0.0f);
      unsigned long long key =
          ((unsigned long long)__float_as_uint(bv[t]) << 32) |
          (unsigned long long)(0xFFFFFFFFu - bj[t]);
      if (valid && key > best) best = key;
    }
#pragma unroll
    for (int d = 32; d >= 1; d >>= 1) {
      unsigned long long o = __shfl_xor(best, d);
      if (o > best) best = o;
    }
    unsigned wj = 0xFFFFFFFFu - (unsigned)(best & 0xFFFFFFFFull);
    if (lane == 0) t8i[row * 8 + pick] = wj;
#pragma unroll
    for (int t = 0; t < 8; ++t) if (bj[t] == wj) bv[t] = -1.0f;
  }
}

// ------- fp64-exact rerank of the 8 candidates -> exact top-4 — r14 verbatim -------
__global__ __launch_bounds__(256) void rerank_k(const float* __restrict__ L,
                                                const float* __restrict__ U,
                                                const double* __restrict__ sqd,
                                                const unsigned* __restrict__ t8i,
                                                unsigned* __restrict__ t4i) {
  const int wave = threadIdx.x >> 6, lane = threadIdx.x & 63;
  const int row = blockIdx.x * 4 + wave;
  const float* xi = xrow(L, U, row);
  float xr[16];
#pragma unroll
  for (int t = 0; t < 16; ++t) xr[t] = xi[t * 64 + lane];
  unsigned cj[8];
  double cw[8];
#pragma unroll
  for (int c = 0; c < 8; ++c) cj[c] = t8i[row * 8 + c];
  for (int c = 0; c < 8; ++c) {
    const float* xj = xrow(L, U, (int)cj[c]);
    double s = 0.0;
#pragma unroll
    for (int t = 0; t < 16; ++t) s += (double)xr[t] * xj[t * 64 + lane];
#pragma unroll
    for (int d = 32; d >= 1; d >>= 1) s += __shfl_xor(s, d);
    double dist = (sqd[row] + sqd[cj[c]] - 2.0 * s) * (1.0 / 1024.0);
    cw[c] = exp(-0.5 * dist);
  }
  if (lane == 0) {
#pragma unroll
    for (int pick = 0; pick < 4; ++pick) {
      int ms = -1;
      double mv = -1.0;
      unsigned mj = 0xFFFFFFFFu;
#pragma unroll
      for (int c = 0; c < 8; ++c) {
        bool better = (cw[c] > mv) || (cw[c] == mv && cj[c] < mj);
        if (cw[c] >= 0.0 && better) { mv = cw[c]; mj = cj[c]; ms = c; }
      }
      t4i[row * 4 + pick] = mj;
      cw[ms] = -2.0;
    }
  }
}

// ------- count kept edges per row from t4i only (mask semantics) -------
__global__ __launch_bounds__(256) void cnt4_k(const unsigned* __restrict__ t4i,
                                              unsigned* __restrict__ nn) {
  const int wave = threadIdx.x >> 6, lane = threadIdx.x & 63;
  const int i = blockIdx.x * 4 + wave;
  const uint4 mine = ((const uint4*)t4i)[i];
  unsigned base = 0;
  for (int j0 = 0; j0 < N_ALL; j0 += 64) {
    int j = j0 + lane;
    uint4 tj = ((const uint4*)t4i)[j];
    bool keep = (mine.x == (unsigned)j) | (mine.y == (unsigned)j) |
                (mine.z == (unsigned)j) | (mine.w == (unsigned)j) |
                (tj.x == (unsigned)i) | (tj.y == (unsigned)i) |
                (tj.z == (unsigned)i) | (tj.w == (unsigned)i);
    keep = keep && (j != i);
    base += (unsigned)__popcll(__ballot(keep));
  }
  if (lane == 0) nn[i] = base;
}

// ------- exclusive scan of nn -> CSR rowPtr — r14 verbatim -------
__global__ __launch_bounds__(64) void scanP_k(const unsigned* __restrict__ nn,
                                              unsigned* __restrict__ rowPtr) {
  const int lane = threadIdx.x;
  unsigned running = 0;
  for (int j0 = 0; j0 < N_ALL; j0 += 64) {
    int v = (int)nn[j0 + lane];
    int incl = v;
#pragma unroll
    for (int d = 1; d < 64; d <<= 1) {
      int t = __shfl_up(incl, d);
      if (lane >= d) incl += t;
    }
    rowPtr[j0 + lane] = running + (unsigned)(incl - v);
    running += (unsigned)__shfl(incl, 63);
  }
  if (lane == 0) rowPtr[N_ALL] = running;
}

// ------- CSR index fill from t4i (j-ascending), values filled later -------
__global__ __launch_bounds__(256) void csrfill_k(const unsigned* __restrict__ t4i,
                                                 const unsigned* __restrict__ rowPtr,
                                                 Edge* __restrict__ edges,
                                                 unsigned* __restrict__ eRow) {
  const int wave = threadIdx.x >> 6, lane = threadIdx.x & 63;
  const int i = blockIdx.x * 4 + wave;
  const uint4 mine = ((const uint4*)t4i)[i];
  unsigned base = rowPtr[i];
  for (int j0 = 0; j0 < N_ALL; j0 += 64) {
    int j = j0 + lane;
    uint4 tj = ((const uint4*)t4i)[j];
    bool keep = (mine.x == (unsigned)j) | (mine.y == (unsigned)j) |
                (mine.z == (unsigned)j) | (mine.w == (unsigned)j) |
                (tj.x == (unsigned)i) | (tj.y == (unsigned)i) |
                (tj.z == (unsigned)i) | (tj.w == (unsigned)i);
    keep = keep && (j != i);
    unsigned long long m = __ballot(keep);
    if (keep) {
      unsigned pos = base + (unsigned)__popcll(m & ((1ull << lane) - 1ull));
      edges[pos].j = (unsigned)j;
      edges[pos].w = 0.0f;
      eRow[pos] = (unsigned)i;
    }
    base += (unsigned)__popcll(m);
  }
}

// ------- exact edge values: fp64-accumulated dot of fp32 inputs, wave/edge -------
__global__ __launch_bounds__(256) void edgeval_k(const float* __restrict__ L,
                                                 const float* __restrict__ U,
                                                 const double* __restrict__ sqd,
                                                 const unsigned* __restrict__ rowPtr,
                                                 const unsigned* __restrict__ eRow,
                                                 Edge* __restrict__ edges) {
  const int wave = threadIdx.x >> 6, lane = threadIdx.x & 63;
  const unsigned e = blockIdx.x * 4 + wave;
  if (e >= rowPtr[N_ALL]) return;
  const unsigned i = eRow[e];
  const unsigned j = edges[e].j;
  const float* xi = xrow(L, U, (int)i);
  const float* xj = xrow(L, U, (int)j);
  double s = 0.0;
#pragma unroll
  for (int t = 0; t < 16; ++t)
    s += (double)xi[t * 64 + lane] * xj[t * 64 + lane];
#pragma unroll
  for (int d = 32; d >= 1; d >>= 1) s += __shfl_xor(s, d);
  if (lane == 0) {
    double dist = (sqd[i] + sqd[j] - 2.0 * s) * (1.0 / 1024.0);
    edges[e].w = (float)exp(-0.5 * dist);
  }
}

// ------- degrees from exact edge values (fp64), wave per row -------
__global__ __launch_bounds__(256) void degE_k(const unsigned* __restrict__ rowPtr,
                                              const Edge* __restrict__ edges,
                                              float* __restrict__ Dis) {
  const int wave = threadIdx.x >> 6, lane = threadIdx.x & 63;
  const int i = blockIdx.x * 4 + wave;
  const unsigned b0 = rowPtr[i], b1 = rowPtr[i + 1];
  double ds = 0.0;
  for (unsigned e = b0 + lane; e < b1; e += 64) ds += (double)edges[e].w;
#pragma unroll
  for (int d = 32; d >= 1; d >>= 1) ds += __shfl_xor(ds, d);
  if (lane == 0) Dis[i] = (float)sqrt(1.0 / (ds + EPS_D));
}

// ------- scale edges: w = (w * Dis_i) * Dis_j -------
__global__ __launch_bounds__(256) void scaleE_k(const unsigned* __restrict__ rowPtr,
                                                const unsigned* __restrict__ eRow,
                                                const float* __restrict__ Dis,
                                                Edge* __restrict__ edges) {
  const unsigned e = blockIdx.x * 256 + threadIdx.x;
  if (e >= rowPtr[N_ALL]) return;
  Edge ed = edges[e];
  edges[e].w = ed.w * Dis[eRow[e]] * Dis[ed.j];
}

// ------- Chebyshev state init — r14 verbatim -------
__global__ __launch_bounds__(256) void init_k(const int* __restrict__ lab,
                                              const int* __restrict__ labflag,
                                              float2* __restrict__ x,
                                              float2* __restrict__ r,
                                              float2* __restrict__ d) {
  const int m = blockIdx.x * 256 + threadIdx.x;
  const int isI64 = labflag[0];
  float2 b = make_float2(0.0f, 0.0f);
  if (m < N_LAB) {
    int c = isI64 ? lab[2 * m] : lab[m];
    b.x = (c == 0) ? 1.0f : 0.0f;
    b.y = (c == 1) ? 1.0f : 0.0f;
  }
  x[m] = make_float2(0.0f, 0.0f);
  r[m] = b;
  d[m] = b;
}

// ---- one Chebyshev iteration — r14 verbatim ----
__global__ __launch_bounds__(512) void chebit_k(const Edge* __restrict__ edges,
                                                const unsigned* __restrict__ rowPtr,
                                                const float2* __restrict__ dIn,
                                                float2* __restrict__ dOut,
                                                float2* __restrict__ x,
                                                float2* __restrict__ r,
                                                float c1, float c2, int last) {
  const int row = blockIdx.x * 8 + (threadIdx.x >> 6);
  const int lane = threadIdx.x & 63;
  const unsigned b0 = rowPtr[row], b1 = rowPtr[row + 1];
  float ax = 0.0f, ay = 0.0f;
  for (unsigned e = b0 + lane; e < b1; e += 64) {
    Edge ed = edges[e];
    float2 dj = dIn[ed.j];
    ax += ed.w * dj.x;
    ay += ed.w * dj.y;
  }
#pragma unroll
  for (int d = 32; d >= 1; d >>= 1) {
    ax += __shfl_xor(ax, d);
    ay += __shfl_xor(ay, d);
  }
  if (lane == 0) {
    float2 di = dIn[row], xi = x[row], ri = r[row];
    xi.x += di.x; xi.y += di.y;
    ri.x += ALPHA_ * ax - di.x;
    ri.y += ALPHA_ * ay - di.y;
    x[row] = xi;
    r[row] = ri;
    if (!last) {
      float2 dn;
      dn.x = c1 * di.x + c2 * ri.x;
      dn.y = c1 * di.y + c2 * ri.y;
      dOut[row] = dn;
    }
  }
}

// ------- emit queries — r14 verbatim -------
__global__ __launch_bounds__(256) void out_k(const float2* __restrict__ x,
                                             float2* __restrict__ out) {
  const int q = blockIdx.x * 256 + threadIdx.x;
  out[q] = x[N_LAB + q];
}

// ---------------- launch ----------------
extern "C" void kernel_launch(void* const* d_in, const int* in_sizes, int n_in,
                              void* d_out, int out_size, void* d_ws, size_t ws_size,
                              hipStream_t stream) {
  int iL = 0, iT = 1, iU = 2;
  for (int i = 0; i < n_in; ++i) {
    if (in_sizes[i] == N_LAB * DIMF) iL = i;
    else if (in_sizes[i] == (N_ALL - N_LAB) * DIMF) iU = i;
    else iT = i;
  }
  const float* L = (const float*)d_in[iL];
  const int* lab = (const int*)d_in[iT];
  const float* U = (const float*)d_in[iU];
  float2* out = (float2*)d_out;

  char* w = (char*)d_ws;
  size_t off = 0;
  auto alloc = [&](size_t bytes) {
    void* p = (void*)(w + off);
    off += (bytes + 255) & ~(size_t)255;
    return p;
  };
  float* W = (float*)alloc((size_t)N_ALL * N_ALL * 4);            // 64 MB
  unsigned short* Xbf = (unsigned short*)alloc((size_t)N_ALL * DIMF * 2);  // 8 MB
  float* sq = (float*)alloc(N_ALL * 4);
  double* sqd = (double*)alloc(N_ALL * 8);
  unsigned* t8i = (unsigned*)alloc(N_ALL * 8 * 4);
  unsigned* t4i = (unsigned*)alloc(N_ALL * 4 * 4);
  float* Dis = (float*)alloc(N_ALL * 4);
  unsigned* nn = (unsigned*)alloc(N_ALL * 4);
  unsigned* rowPtr = (unsigned*)alloc((N_ALL + 1) * 4);
  int* labflag = (int*)alloc(256);
  Edge* edges = (Edge*)alloc((size_t)EDGECAP * sizeof(Edge));     // 256 KB
  unsigned* eRow = (unsigned*)alloc((size_t)EDGECAP * 4);         // 128 KB
  float2* xv = (float2*)alloc(N_ALL * 8);
  float2* rv = (float2*)alloc(N_ALL * 8);
  float2* dv0 = (float2*)alloc(N_ALL * 8);
  float2* dv1 = (float2*)alloc(N_ALL * 8);
  if (off > ws_size) return;

  labfmt_k<<<1, 256, 0, stream>>>(lab, labflag);
  prep_k<<<N_ALL, 256, 0, stream>>>(L, U, Xbf, sq, sqd);
  gemm_w<<<dim3(32, 32), 256, 0, stream>>>(Xbf, sq, W);
  top8_k<<<N_ALL / 4, 256, 0, stream>>>(W, t8i);
  rerank_k<<<N_ALL / 4, 256, 0, stream>>>(L, U, sqd, t8i, t4i);
  cnt4_k<<<N_ALL / 4, 256, 0, stream>>>(t4i, nn);
  scanP_k<<<1, 64, 0, stream>>>(nn, rowPtr);
  csrfill_k<<<N_ALL / 4, 256, 0, stream>>>(t4i, rowPtr, edges, eRow);
  edgeval_k<<<EDGECAP / 4, 256, 0, stream>>>(L, U, sqd, rowPtr, eRow, edges);
  degE_k<<<N_ALL / 4, 256, 0, stream>>>(rowPtr, edges, Dis);
  scaleE_k<<<EDGECAP / 256, 256, 0, stream>>>(rowPtr, eRow, Dis, edges);
  init_k<<<N_ALL / 256, 256, 0, stream>>>(lab, labflag, xv, rv, dv0);

  const double theta = 1.0, delta = 0.992;
  const double sigma1 = theta / delta;
  double rho = delta / theta;
  float2* dA = dv0;
  float2* dB = dv1;
  for (int k = 0; k < NIT_CH; ++k) {
    const int last = (k == NIT_CH - 1);
    const double rho_new = 1.0 / (2.0 * sigma1 - rho);
    const float c1 = (float)(rho_new * rho);
    const float c2 = (float)(2.0 * rho_new / delta);
    chebit_k<<<N_ALL / 8, 512, 0, stream>>>(edges, rowPtr, dA, dB, xv, rv,
                                            c1, c2, last);
    rho = rho_new;
    float2* t = dA; dA = dB; dB = t;
  }
  out_k<<<(N_ALL - N_LAB) / 256, 256, 0, stream>>>(xv, out);
}